// Round 8
// baseline (610.689 us; speedup 1.0000x reference)
//
#include <hip/hip_runtime.h>
#include <math.h>

#define DD 256      // input/hidden feature dim
#define LL 40       // output classes
#define NSLOPE 0.2f // PyG GATConv leaky_relu slope
#define SCHUNK 1024 // elements per scan block (n<=64*SCHUNK)

typedef unsigned short u16;
typedef unsigned int uint;
typedef __attribute__((ext_vector_type(8))) short short8;
typedef __attribute__((ext_vector_type(4))) float f32x4;

__device__ __forceinline__ float bf2f(u16 v) { return __uint_as_float(((uint)v) << 16); }
__device__ __forceinline__ u16 f2bf(float f) {
  uint u = __float_as_uint(f);
  return (u16)((u + 0x7fff + ((u >> 16) & 1)) >> 16);  // RNE
}
__device__ __forceinline__ void acc8(float* a, uint4 v) {
  a[0] += __uint_as_float(v.x << 16);
  a[1] += __uint_as_float(v.x & 0xffff0000u);
  a[2] += __uint_as_float(v.y << 16);
  a[3] += __uint_as_float(v.y & 0xffff0000u);
  a[4] += __uint_as_float(v.z << 16);
  a[5] += __uint_as_float(v.z & 0xffff0000u);
  a[6] += __uint_as_float(v.w << 16);
  a[7] += __uint_as_float(v.w & 0xffff0000u);
}
__device__ __forceinline__ void wacc8(float* a, uint4 v, float w) {
  a[0] += w * __uint_as_float(v.x << 16);
  a[1] += w * __uint_as_float(v.x & 0xffff0000u);
  a[2] += w * __uint_as_float(v.y << 16);
  a[3] += w * __uint_as_float(v.y & 0xffff0000u);
  a[4] += w * __uint_as_float(v.z << 16);
  a[5] += w * __uint_as_float(v.z & 0xffff0000u);
  a[6] += w * __uint_as_float(v.w << 16);
  a[7] += w * __uint_as_float(v.w & 0xffff0000u);
}

// ---------------- column stats (mean/std, ddof=1) ----------------
// wave reads a full 1KB row (64 lanes x float4); 4 waves = 4 rows in flight; LDS tree-reduce;
// one global atomicAdd per column per block (same contention as before, 4x the bytes/instr)
__global__ __launch_bounds__(256) void k_colstats(const float* __restrict__ x, float* __restrict__ csum,
                                                  float* __restrict__ csq, int n, int rowsPerBlk) {
  __shared__ float4 sS[256];
  __shared__ float4 sQ[256];
  int tid = threadIdx.x;
  int c4 = tid & 63;     // float4 column group (lane)
  int rsub = tid >> 6;   // wave id = row sub-offset
  int base = blockIdx.x * rowsPerBlk;
  int r1 = min(base + rowsPerBlk, n);
  float4 s = make_float4(0.f, 0.f, 0.f, 0.f);
  float4 q = make_float4(0.f, 0.f, 0.f, 0.f);
  for (int r = base + rsub; r < r1; r += 4) {
    float4 v = ((const float4*)x)[(size_t)r * (DD / 4) + c4];
    s.x += v.x; s.y += v.y; s.z += v.z; s.w += v.w;
    q.x += v.x * v.x; q.y += v.y * v.y; q.z += v.z * v.z; q.w += v.w * v.w;
  }
  sS[tid] = s;
  sQ[tid] = q;
  __syncthreads();
  if (tid < 64) {  // reduce 4 waves' partials for columns tid*4..+3, then global atomics
    float4 a0 = sS[tid], a1 = sS[tid + 64], a2 = sS[tid + 128], a3 = sS[tid + 192];
    atomicAdd(&csum[tid * 4 + 0], a0.x + a1.x + a2.x + a3.x);
    atomicAdd(&csum[tid * 4 + 1], a0.y + a1.y + a2.y + a3.y);
    atomicAdd(&csum[tid * 4 + 2], a0.z + a1.z + a2.z + a3.z);
    atomicAdd(&csum[tid * 4 + 3], a0.w + a1.w + a2.w + a3.w);
  } else if (tid < 128) {
    int t = tid - 64;
    float4 a0 = sQ[t], a1 = sQ[t + 64], a2 = sQ[t + 128], a3 = sQ[t + 192];
    atomicAdd(&csq[t * 4 + 0], a0.x + a1.x + a2.x + a3.x);
    atomicAdd(&csq[t * 4 + 1], a0.y + a1.y + a2.y + a3.y);
    atomicAdd(&csq[t * 4 + 2], a0.z + a1.z + a2.z + a3.z);
    atomicAdd(&csq[t * 4 + 3], a0.w + a1.w + a2.w + a3.w);
  }
}

__global__ void k_finalize_stats(const float* __restrict__ csum, const float* __restrict__ csq,
                                 float* __restrict__ mean, float* __restrict__ rstd, int n) {
  int j = threadIdx.x;
  float s = csum[j], q = csq[j];
  float m = s / (float)n;
  float var = (q - s * m) / (float)(n - 1);   // unbiased, ddof=1
  mean[j] = m;
  rstd[j] = 1.0f / sqrtf(var);
}

// standardize and cast to bf16
__global__ void k_standardize(const float* __restrict__ x, const float* __restrict__ mean,
                              const float* __restrict__ rstd, u16* __restrict__ xs, int total4) {
  int i = blockIdx.x * blockDim.x + threadIdx.x;
  if (i >= total4) return;
  int c4 = i & (DD / 4 - 1);
  float4 v = ((const float4*)x)[i];
  float4 m = ((const float4*)mean)[c4];
  float4 r = ((const float4*)rstd)[c4];
  uint2 o;
  o.x = (uint)f2bf((v.x - m.x) * r.x) | ((uint)f2bf((v.y - m.y) * r.y) << 16);
  o.y = (uint)f2bf((v.z - m.z) * r.z) | ((uint)f2bf((v.w - m.w) * r.w) << 16);
  ((uint2*)xs)[i] = o;
}

// ---------------- weight fp32 [K][N] -> bf16 transposed [N][K] ----------------
__global__ void k_convWt(const float* __restrict__ W, u16* __restrict__ Wt, int K, int N) {
  int k = blockIdx.x;
  for (int nn = threadIdx.x; nn < N; nn += blockDim.x)
    Wt[(size_t)nn * K + k] = f2bf(W[(size_t)k * N + nn]);
}

// ---------------- CSR build (by destination, self-loop appended per row) ----------------
__global__ void k_count_deg(const int* __restrict__ edst, int E, int* __restrict__ degi) {
  int i = blockIdx.x * blockDim.x + threadIdx.x;
  if (i < E) atomicAdd(&degi[edst[i]], 1);
}

// per-chunk sums of (deg+1)
__global__ __launch_bounds__(256) void k_blocksum(const int* __restrict__ degi, int* __restrict__ bsum, int n) {
  int b = blockIdx.x, tid = threadIdx.x;
  int base = b * SCHUNK;
  int end = min(base + SCHUNK, n);
  int s = 0;
  for (int i = base + tid; i < end; i += 256) s += degi[i] + 1;
  __shared__ int ws[4];
  #pragma unroll
  for (int off = 32; off >= 1; off >>= 1) s += __shfl_down(s, off);
  if ((tid & 63) == 0) ws[tid >> 6] = s;
  __syncthreads();
  if (tid == 0) bsum[b] = ws[0] + ws[1] + ws[2] + ws[3];
}

// exclusive scan of <=64 block sums, one wave
__global__ void k_scan_bsums(int* __restrict__ bsum, int nb) {
  int lane = threadIdx.x;  // 64 threads
  int orig = (lane < nb) ? bsum[lane] : 0;
  int v = orig;
  #pragma unroll
  for (int off = 1; off < 64; off <<= 1) {
    int t = __shfl_up(v, off);
    if (lane >= off) v += t;
  }
  if (lane < nb) bsum[lane] = v - orig;  // exclusive
}

// chunk-local scan + global offset -> rowptr, cursor, dinv
__global__ __launch_bounds__(256) void k_rowptr_write(const int* __restrict__ degi, const int* __restrict__ bsum,
                                                      int* __restrict__ rowptr, int* __restrict__ cursor,
                                                      float* __restrict__ dinv, int n) {
  int b = blockIdx.x, tid = threadIdx.x;
  int base = b * SCHUNK + tid * 4;
  int d[4];
  int t = 0;
  #pragma unroll
  for (int j = 0; j < 4; ++j) {
    int i = base + j;
    d[j] = (i < n) ? degi[i] + 1 : 0;
    t += d[j];
  }
  __shared__ int sc[256];
  sc[tid] = t;
  __syncthreads();
  for (int off = 1; off < 256; off <<= 1) {
    int v = 0;
    if (tid >= off) v = sc[tid - off];
    __syncthreads();
    if (tid >= off) sc[tid] += v;
    __syncthreads();
  }
  int run = bsum[b] + sc[tid] - t;
  #pragma unroll
  for (int j = 0; j < 4; ++j) {
    int i = base + j;
    if (i < n) {
      rowptr[i] = run;
      cursor[i] = run;
      dinv[i] = rsqrtf((float)d[j]);
      run += d[j];
      if (i == n - 1) rowptr[n] = run;
    }
  }
}

__global__ void k_scatter(const int* __restrict__ esrc, const int* __restrict__ edst, int E,
                          int* __restrict__ cursor, int* __restrict__ csrsrc) {
  int i = blockIdx.x * blockDim.x + threadIdx.x;
  if (i < E) {
    int d = edst[i];
    int p = atomicAdd(&cursor[d], 1);
    csrsrc[p] = esrc[i];
  }
}

__global__ void k_selfloop(const int* __restrict__ rowptr, int* __restrict__ csrsrc, int n) {
  int i = blockIdx.x * blockDim.x + threadIdx.x;
  if (i < n) csrsrc[rowptr[i + 1] - 1] = i;
}

// ---------------- bf16 MFMA GEMM, 128x128 tile (N multiple of 128): C = A @ Bt^T ----------------
__global__ __launch_bounds__(256) void k_mfma_gemm128(const u16* __restrict__ A, const u16* __restrict__ Bt,
                                                      u16* __restrict__ C, int M, int N, int K,
                                                      const float* __restrict__ rowScale) {
  __shared__ u16 As[128 * 40];  // [128][32+8] pad -> 2-way (free) LDS banking
  __shared__ u16 Bs[128 * 40];
  int tid = threadIdx.x;
  int wave = tid >> 6, lane = tid & 63, quad = lane >> 4, l16 = lane & 15;
  int rowBase = blockIdx.y * 128, colBase = blockIdx.x * 128;
  f32x4 acc[2][8] = {};
  for (int k0 = 0; k0 < K; k0 += 32) {
    #pragma unroll
    for (int i = 0; i < 2; ++i) {
      int ch = tid + i * 256;
      int r = ch >> 2, cc = (ch & 3) * 8;
      int gr = min(rowBase + r, M - 1);  // clamp: junk rows never stored
      *(uint4*)&As[r * 40 + cc] = *(const uint4*)(A + (size_t)gr * K + k0 + cc);
      *(uint4*)&Bs[r * 40 + cc] = *(const uint4*)(Bt + (size_t)(colBase + r) * K + k0 + cc);
    }
    __syncthreads();
    short8 af0 = *(const short8*)&As[(wave * 32 + l16) * 40 + quad * 8];
    short8 af1 = *(const short8*)&As[(wave * 32 + 16 + l16) * 40 + quad * 8];
    #pragma unroll
    for (int j = 0; j < 8; ++j) {
      short8 bf = *(const short8*)&Bs[(j * 16 + l16) * 40 + quad * 8];
      acc[0][j] = __builtin_amdgcn_mfma_f32_16x16x32_bf16(af0, bf, acc[0][j], 0, 0, 0);
      acc[1][j] = __builtin_amdgcn_mfma_f32_16x16x32_bf16(af1, bf, acc[1][j], 0, 0, 0);
    }
    __syncthreads();
  }
  // C/D layout: col=lane&15, row=quad*4+reg
  #pragma unroll
  for (int i = 0; i < 2; ++i) {
    #pragma unroll
    for (int r = 0; r < 4; ++r) {
      int gr = rowBase + wave * 32 + i * 16 + quad * 4 + r;
      if (gr >= M) continue;
      float sc = rowScale ? rowScale[gr] : 1.0f;
      #pragma unroll
      for (int j = 0; j < 8; ++j) {
        int gc = colBase + j * 16 + l16;
        C[(size_t)gr * N + gc] = f2bf(acc[i][j][r] * sc);
      }
    }
  }
}

// ---------------- bf16 MFMA GEMM, 128x64 tile (generic N, used for final W2) ----------------
__global__ __launch_bounds__(256) void k_mfma_gemm(const u16* __restrict__ A, const u16* __restrict__ Bt,
                                                   u16* __restrict__ C, int M, int N, int K,
                                                   const float* __restrict__ rowScale) {
  __shared__ u16 As[128 * 40];
  __shared__ u16 Bs[64 * 40];
  int tid = threadIdx.x;
  int wave = tid >> 6, lane = tid & 63, quad = lane >> 4, l16 = lane & 15;
  int rowBase = blockIdx.y * 128, colBase = blockIdx.x * 64;
  f32x4 acc[2][4] = {};
  for (int k0 = 0; k0 < K; k0 += 32) {
    #pragma unroll
    for (int i = 0; i < 2; ++i) {
      int ch = tid + i * 256;
      int r = ch >> 2, cc = (ch & 3) * 8;
      int gr = rowBase + r;
      uint4 v = make_uint4(0, 0, 0, 0);
      if (gr < M) v = *(const uint4*)(A + (size_t)gr * K + k0 + cc);
      *(uint4*)&As[r * 40 + cc] = v;
    }
    {
      int r = tid >> 2, cc = (tid & 3) * 8;
      int gn = colBase + r;
      uint4 v = make_uint4(0, 0, 0, 0);
      if (gn < N) v = *(const uint4*)(Bt + (size_t)gn * K + k0 + cc);
      *(uint4*)&Bs[r * 40 + cc] = v;
    }
    __syncthreads();
    short8 af[2];
    af[0] = *(const short8*)&As[(wave * 32 + l16) * 40 + quad * 8];
    af[1] = *(const short8*)&As[(wave * 32 + 16 + l16) * 40 + quad * 8];
    short8 bf[4];
    #pragma unroll
    for (int j = 0; j < 4; ++j) bf[j] = *(const short8*)&Bs[(j * 16 + l16) * 40 + quad * 8];
    #pragma unroll
    for (int i = 0; i < 2; ++i)
      #pragma unroll
      for (int j = 0; j < 4; ++j)
        acc[i][j] = __builtin_amdgcn_mfma_f32_16x16x32_bf16(af[i], bf[j], acc[i][j], 0, 0, 0);
    __syncthreads();
  }
  #pragma unroll
  for (int i = 0; i < 2; ++i) {
    #pragma unroll
    for (int r = 0; r < 4; ++r) {
      int gr = rowBase + wave * 32 + i * 16 + quad * 4 + r;
      if (gr >= M) continue;
      float sc = rowScale ? rowScale[gr] : 1.0f;
      #pragma unroll
      for (int j = 0; j < 4; ++j) {
        int gc = colBase + j * 16 + l16;
        if (gc < N) C[(size_t)gr * N + gc] = f2bf(acc[i][j][r] * sc);
      }
    }
  }
}

// ---------------- GCN aggregate (rows pre-scaled by dinv[s]): out[d]=relu(dinv[d]*sum + b) ----------------
__global__ __launch_bounds__(256) void k_gcn_agg(const u16* __restrict__ hs, const int* __restrict__ rowptr,
                                                 const int* __restrict__ csrsrc, const float* __restrict__ dinv,
                                                 const float* __restrict__ bias, u16* __restrict__ out, int n) {
  int wave = (blockIdx.x * blockDim.x + threadIdx.x) >> 6;
  int lane = threadIdx.x & 63;
  int sub = lane >> 5, l = lane & 31;
  int w = wave * 2 + sub;
  if (w >= n) return;
  int p0 = rowptr[w], p1 = rowptr[w + 1];
  float a[8] = {};
  int p = p0;
  for (; p + 4 <= p1; p += 4) {
    int s0 = csrsrc[p], s1 = csrsrc[p + 1], s2 = csrsrc[p + 2], s3 = csrsrc[p + 3];
    uint4 v0 = *(const uint4*)(hs + (size_t)s0 * DD + l * 8);
    uint4 v1 = *(const uint4*)(hs + (size_t)s1 * DD + l * 8);
    uint4 v2 = *(const uint4*)(hs + (size_t)s2 * DD + l * 8);
    uint4 v3 = *(const uint4*)(hs + (size_t)s3 * DD + l * 8);
    acc8(a, v0); acc8(a, v1); acc8(a, v2); acc8(a, v3);
  }
  for (; p < p1; ++p) {
    int s = csrsrc[p];
    uint4 v = *(const uint4*)(hs + (size_t)s * DD + l * 8);
    acc8(a, v);
  }
  float dd = dinv[w];
  float4 b0 = ((const float4*)bias)[l * 2];
  float4 b1 = ((const float4*)bias)[l * 2 + 1];
  float r0 = fmaxf(dd * a[0] + b0.x, 0.f), r1 = fmaxf(dd * a[1] + b0.y, 0.f);
  float r2 = fmaxf(dd * a[2] + b0.z, 0.f), r3 = fmaxf(dd * a[3] + b0.w, 0.f);
  float r4 = fmaxf(dd * a[4] + b1.x, 0.f), r5 = fmaxf(dd * a[5] + b1.y, 0.f);
  float r6 = fmaxf(dd * a[6] + b1.z, 0.f), r7 = fmaxf(dd * a[7] + b1.w, 0.f);
  uint4 o;
  o.x = (uint)f2bf(r0) | ((uint)f2bf(r1) << 16);
  o.y = (uint)f2bf(r2) | ((uint)f2bf(r3) << 16);
  o.z = (uint)f2bf(r4) | ((uint)f2bf(r5) << 16);
  o.w = (uint)f2bf(r6) | ((uint)f2bf(r7) << 16);
  *(uint4*)(out + (size_t)w * DD + l * 8) = o;
}

// ---------------- GAT: per-node attention logits al = h . a ----------------
__global__ __launch_bounds__(256) void k_al(const u16* __restrict__ h, const float* __restrict__ va,
                                            const float* __restrict__ vb, float* __restrict__ als,
                                            float* __restrict__ ald, int n) {
  int w = (blockIdx.x * blockDim.x + threadIdx.x) >> 6;
  int lane = threadIdx.x & 63;
  if (w >= n) return;
  uint2 v = *(const uint2*)(h + (size_t)w * DD + lane * 4);
  float x0 = __uint_as_float(v.x << 16), x1 = __uint_as_float(v.x & 0xffff0000u);
  float x2 = __uint_as_float(v.y << 16), x3 = __uint_as_float(v.y & 0xffff0000u);
  float4 a = ((const float4*)va)[lane];
  float4 b = ((const float4*)vb)[lane];
  float s1 = x0 * a.x + x1 * a.y + x2 * a.z + x3 * a.w;
  float s2 = x0 * b.x + x1 * b.y + x2 * b.z + x3 * b.w;
  #pragma unroll
  for (int off = 1; off < 64; off <<= 1) {
    s1 += __shfl_xor(s1, off);
    s2 += __shfl_xor(s2, off);
  }
  if (lane == 0) { als[w] = s1; ald[w] = s2; }
}

// ---------------- GAT aggregate: online segment softmax + weighted sum + bias + relu ----------------
__global__ __launch_bounds__(256) void k_gat_agg(const u16* __restrict__ h, const int* __restrict__ rowptr,
                                                 const int* __restrict__ csrsrc, const float* __restrict__ als,
                                                 const float* __restrict__ ald, const float* __restrict__ bias,
                                                 u16* __restrict__ out, int n) {
  int wave = (blockIdx.x * blockDim.x + threadIdx.x) >> 6;
  int lane = threadIdx.x & 63;
  int sub = lane >> 5, l = lane & 31;
  int w = wave * 2 + sub;
  if (w >= n) return;
  float ad = ald[w];
  int p0 = rowptr[w], p1 = rowptr[w + 1];
  // pass 1: online softmax stats, lanes stride edges within half-wave
  float m = -1e30f, z = 0.f;
  for (int p = p0 + l; p < p1; p += 32) {
    float e = als[csrsrc[p]] + ad;
    e = (e > 0.f) ? e : NSLOPE * e;
    if (e > m) { z = z * __expf(m - e) + 1.f; m = e; }
    else z += __expf(e - m);
  }
  #pragma unroll
  for (int off = 16; off >= 1; off >>= 1) {
    float m2 = __shfl_xor(m, off), z2 = __shfl_xor(z, off);
    float M = fmaxf(m, m2);
    z = z * __expf(m - M) + z2 * __expf(m2 - M);
    m = M;
  }
  float invz = 1.0f / z;
  // pass 2: weighted feature accumulation, lane owns 8 features, unroll x4
  float a[8] = {};
  int p = p0;
  for (; p + 4 <= p1; p += 4) {
    int s0 = csrsrc[p], s1 = csrsrc[p + 1], s2 = csrsrc[p + 2], s3 = csrsrc[p + 3];
    float e0 = als[s0] + ad; e0 = (e0 > 0.f) ? e0 : NSLOPE * e0;
    float e1 = als[s1] + ad; e1 = (e1 > 0.f) ? e1 : NSLOPE * e1;
    float e2 = als[s2] + ad; e2 = (e2 > 0.f) ? e2 : NSLOPE * e2;
    float e3 = als[s3] + ad; e3 = (e3 > 0.f) ? e3 : NSLOPE * e3;
    uint4 v0 = *(const uint4*)(h + (size_t)s0 * DD + l * 8);
    uint4 v1 = *(const uint4*)(h + (size_t)s1 * DD + l * 8);
    uint4 v2 = *(const uint4*)(h + (size_t)s2 * DD + l * 8);
    uint4 v3 = *(const uint4*)(h + (size_t)s3 * DD + l * 8);
    wacc8(a, v0, __expf(e0 - m) * invz);
    wacc8(a, v1, __expf(e1 - m) * invz);
    wacc8(a, v2, __expf(e2 - m) * invz);
    wacc8(a, v3, __expf(e3 - m) * invz);
  }
  for (; p < p1; ++p) {
    int s = csrsrc[p];
    float e = als[s] + ad; e = (e > 0.f) ? e : NSLOPE * e;
    uint4 v = *(const uint4*)(h + (size_t)s * DD + l * 8);
    wacc8(a, v, __expf(e - m) * invz);
  }
  float4 b0 = ((const float4*)bias)[l * 2];
  float4 b1 = ((const float4*)bias)[l * 2 + 1];
  float r0 = fmaxf(a[0] + b0.x, 0.f), r1 = fmaxf(a[1] + b0.y, 0.f);
  float r2 = fmaxf(a[2] + b0.z, 0.f), r3 = fmaxf(a[3] + b0.w, 0.f);
  float r4 = fmaxf(a[4] + b1.x, 0.f), r5 = fmaxf(a[5] + b1.y, 0.f);
  float r6 = fmaxf(a[6] + b1.z, 0.f), r7 = fmaxf(a[7] + b1.w, 0.f);
  uint4 o;
  o.x = (uint)f2bf(r0) | ((uint)f2bf(r1) << 16);
  o.y = (uint)f2bf(r2) | ((uint)f2bf(r3) << 16);
  o.z = (uint)f2bf(r4) | ((uint)f2bf(r5) << 16);
  o.w = (uint)f2bf(r6) | ((uint)f2bf(r7) << 16);
  *(uint4*)(out + (size_t)w * DD + l * 8) = o;
}

// ---------------- final GCN (H->40, rows pre-scaled by dinv) + log_softmax, fp32 out ----------------
__global__ __launch_bounds__(256) void k_gcn2_lsm(const u16* __restrict__ hs, const int* __restrict__ rowptr,
                                                  const int* __restrict__ csrsrc, const float* __restrict__ dinv,
                                                  const float* __restrict__ bias, float* __restrict__ out, int n) {
  int w = (blockIdx.x * blockDim.x + threadIdx.x) >> 6;
  int lane = threadIdx.x & 63;
  if (w >= n) return;
  int p0 = rowptr[w], p1 = rowptr[w + 1];
  float acc = 0.f;
  int p = p0;
  for (; p + 4 <= p1; p += 4) {
    int s0 = csrsrc[p], s1 = csrsrc[p + 1], s2 = csrsrc[p + 2], s3 = csrsrc[p + 3];
    if (lane < LL) {
      float v0 = bf2f(hs[(size_t)s0 * LL + lane]);
      float v1 = bf2f(hs[(size_t)s1 * LL + lane]);
      float v2 = bf2f(hs[(size_t)s2 * LL + lane]);
      float v3 = bf2f(hs[(size_t)s3 * LL + lane]);
      acc += v0 + v1 + v2 + v3;
    }
  }
  for (; p < p1; ++p) {
    int s = csrsrc[p];
    if (lane < LL) acc += bf2f(hs[(size_t)s * LL + lane]);
  }
  float dd = dinv[w];
  float v = (lane < LL) ? dd * acc + bias[lane] : -INFINITY;
  float m = v;
  #pragma unroll
  for (int off = 1; off < 64; off <<= 1) m = fmaxf(m, __shfl_xor(m, off));
  float ex = (lane < LL) ? __expf(v - m) : 0.f;
  float z = ex;
  #pragma unroll
  for (int off = 1; off < 64; off <<= 1) z += __shfl_xor(z, off);
  if (lane < LL) out[(size_t)w * LL + lane] = v - m - logf(z);
}

// ---------------- launch ----------------
extern "C" void kernel_launch(void* const* d_in, const int* in_sizes, int n_in,
                              void* d_out, int out_size, void* d_ws, size_t ws_size,
                              hipStream_t stream) {
  const float* x   = (const float*)d_in[0];
  const int*   ei  = (const int*)d_in[1];
  const float* W1  = (const float*)d_in[2];
  const float* b1  = (const float*)d_in[3];
  const float* Wg  = (const float*)d_in[4];
  const float* a_s = (const float*)d_in[5];
  const float* a_d = (const float*)d_in[6];
  const float* bg  = (const float*)d_in[7];
  const float* W2  = (const float*)d_in[8];
  const float* b2  = (const float*)d_in[9];
  float* out = (float*)d_out;

  const int n = in_sizes[0] / DD;
  const int E = in_sizes[1] / 2;
  const int M = E + n;
  const int* esrc = ei;
  const int* edst = ei + E;

  char* wp = (char*)d_ws;
  auto carve = [&](size_t bytes) -> char* {
    char* p = wp;
    wp += (bytes + 255) & ~(size_t)255;
    return p;
  };
  u16*   buf0   = (u16*)carve((size_t)n * DD * 2);
  u16*   buf1   = (u16*)carve((size_t)n * DD * 2);
  u16*   h40    = (u16*)carve((size_t)n * LL * 2);
  u16*   W1t    = (u16*)carve((size_t)DD * DD * 2);
  u16*   Wgt    = (u16*)carve((size_t)DD * DD * 2);
  u16*   W2t    = (u16*)carve((size_t)LL * DD * 2);
  int*   csrsrc = (int*)carve((size_t)M * 4);
  int*   rowptr = (int*)carve((size_t)(n + 1) * 4);
  int*   cursor = (int*)carve((size_t)n * 4);
  int*   degi   = (int*)carve((size_t)n * 4);
  int*   bsum   = (int*)carve(64 * 4);
  float* dinv   = (float*)carve((size_t)n * 4);
  float* alsA   = (float*)carve((size_t)n * 4);
  float* aldA   = (float*)carve((size_t)n * 4);
  float* csum   = (float*)carve(DD * 4);
  float* csq    = (float*)carve(DD * 4);
  float* mean   = (float*)carve(DD * 4);
  float* rstd   = (float*)carve(DD * 4);

  hipMemsetAsync(degi, 0, (size_t)n * 4, stream);
  hipMemsetAsync(csum, 0, DD * 4, stream);
  hipMemsetAsync(csq, 0, DD * 4, stream);

  // standardization -> bf16 buf0
  const int rowsPerBlk = 64;
  k_colstats<<<(n + rowsPerBlk - 1) / rowsPerBlk, 256, 0, stream>>>(x, csum, csq, n, rowsPerBlk);
  k_finalize_stats<<<1, DD, 0, stream>>>(csum, csq, mean, rstd, n);
  int total4 = n * (DD / 4);
  k_standardize<<<(total4 + 255) / 256, 256, 0, stream>>>(x, mean, rstd, buf0, total4);

  // weight convert+transpose to bf16
  k_convWt<<<DD, 256, 0, stream>>>(W1, W1t, DD, DD);
  k_convWt<<<DD, 256, 0, stream>>>(Wg, Wgt, DD, DD);
  k_convWt<<<DD, 64, 0, stream>>>(W2, W2t, DD, LL);

  // CSR build — parallel hierarchical scan
  int nb = (n + SCHUNK - 1) / SCHUNK;
  k_count_deg<<<(E + 255) / 256, 256, 0, stream>>>(edst, E, degi);
  k_blocksum<<<nb, 256, 0, stream>>>(degi, bsum, n);
  k_scan_bsums<<<1, 64, 0, stream>>>(bsum, nb);
  k_rowptr_write<<<nb, 256, 0, stream>>>(degi, bsum, rowptr, cursor, dinv, n);
  k_scatter<<<(E + 255) / 256, 256, 0, stream>>>(esrc, edst, E, cursor, csrsrc);
  k_selfloop<<<(n + 255) / 256, 256, 0, stream>>>(rowptr, csrsrc, n);

  dim3 blk(256);
  dim3 gemmGrid(DD / 128, (n + 127) / 128);   // 128x128 tiles for square GEMMs
  int aggGrid1 = (n + 3) / 4;   // 1 wave per node kernels (k_al, k_gcn2_lsm)
  int aggGrid2 = (n + 7) / 8;   // 2 nodes per wave kernels

  // layer 1: GCN(256->256) + relu  (GEMM epilogue pre-scales rows by dinv)
  k_mfma_gemm128<<<gemmGrid, blk, 0, stream>>>(buf0, W1t, buf1, n, DD, DD, dinv);
  k_gcn_agg<<<aggGrid2, blk, 0, stream>>>(buf1, rowptr, csrsrc, dinv, b1, buf0, n);

  // layers 2,3: GAT(256->256) + relu
  for (int l = 0; l < 2; ++l) {
    k_mfma_gemm128<<<gemmGrid, blk, 0, stream>>>(buf0, Wgt, buf1, n, DD, DD, nullptr);
    k_al<<<aggGrid1, blk, 0, stream>>>(buf1, a_s, a_d, alsA, aldA, n);
    k_gat_agg<<<aggGrid2, blk, 0, stream>>>(buf1, rowptr, csrsrc, alsA, aldA, bg, buf0, n);
  }

  // final: GCN(256->40) + log_softmax (rows pre-scaled by dinv)
  dim3 gemmGrid2(1, (n + 127) / 128);
  k_mfma_gemm<<<gemmGrid2, blk, 0, stream>>>(buf0, W2t, h40, n, LL, DD, dinv);
  k_gcn2_lsm<<<aggGrid1, blk, 0, stream>>>(h40, rowptr, csrsrc, dinv, b2, out, n);
}

// Round 9
// 567.958 us; speedup vs baseline: 1.0752x; 1.0752x over previous
//
#include <hip/hip_runtime.h>
#include <math.h>

#define DD 256      // input/hidden feature dim
#define LL 40       // output classes
#define NSLOPE 0.2f // PyG GATConv leaky_relu slope
#define SCHUNK 1024 // elements per scan block (n<=64*SCHUNK)

typedef unsigned short u16;
typedef unsigned int uint;
typedef __attribute__((ext_vector_type(8))) short short8;
typedef __attribute__((ext_vector_type(4))) float f32x4;

__device__ __forceinline__ float bf2f(u16 v) { return __uint_as_float(((uint)v) << 16); }
__device__ __forceinline__ u16 f2bf(float f) {
  uint u = __float_as_uint(f);
  return (u16)((u + 0x7fff + ((u >> 16) & 1)) >> 16);  // RNE
}
__device__ __forceinline__ void acc8(float* a, uint4 v) {
  a[0] += __uint_as_float(v.x << 16);
  a[1] += __uint_as_float(v.x & 0xffff0000u);
  a[2] += __uint_as_float(v.y << 16);
  a[3] += __uint_as_float(v.y & 0xffff0000u);
  a[4] += __uint_as_float(v.z << 16);
  a[5] += __uint_as_float(v.z & 0xffff0000u);
  a[6] += __uint_as_float(v.w << 16);
  a[7] += __uint_as_float(v.w & 0xffff0000u);
}
__device__ __forceinline__ void wacc8(float* a, uint4 v, float w) {
  a[0] += w * __uint_as_float(v.x << 16);
  a[1] += w * __uint_as_float(v.x & 0xffff0000u);
  a[2] += w * __uint_as_float(v.y << 16);
  a[3] += w * __uint_as_float(v.y & 0xffff0000u);
  a[4] += w * __uint_as_float(v.z << 16);
  a[5] += w * __uint_as_float(v.z & 0xffff0000u);
  a[6] += w * __uint_as_float(v.w << 16);
  a[7] += w * __uint_as_float(v.w & 0xffff0000u);
}

// ---------------- column stats (mean/std, ddof=1) ----------------
// thread = column (coalesced 256B/wave); 8 explicit independent loads per iteration for MLP;
// many blocks (rowsPerBlk=32 -> ~1563 blocks, ~24 waves/CU) per R8 post-mortem.
__global__ __launch_bounds__(256) void k_colstats(const float* __restrict__ x, float* __restrict__ csum,
                                                  float* __restrict__ csq, int n, int rowsPerBlk) {
  int col = threadIdx.x;
  int r0 = blockIdx.x * rowsPerBlk;
  int r1 = min(r0 + rowsPerBlk, n);
  float s0 = 0.f, s1 = 0.f, s2 = 0.f, s3 = 0.f;
  float q0 = 0.f, q1 = 0.f, q2 = 0.f, q3 = 0.f;
  const float* xc = x + col;
  int r = r0;
  for (; r + 8 <= r1; r += 8) {
    float v0 = xc[(size_t)(r + 0) * DD];
    float v1 = xc[(size_t)(r + 1) * DD];
    float v2 = xc[(size_t)(r + 2) * DD];
    float v3 = xc[(size_t)(r + 3) * DD];
    float v4 = xc[(size_t)(r + 4) * DD];
    float v5 = xc[(size_t)(r + 5) * DD];
    float v6 = xc[(size_t)(r + 6) * DD];
    float v7 = xc[(size_t)(r + 7) * DD];
    s0 += v0; q0 = fmaf(v0, v0, q0);
    s1 += v1; q1 = fmaf(v1, v1, q1);
    s2 += v2; q2 = fmaf(v2, v2, q2);
    s3 += v3; q3 = fmaf(v3, v3, q3);
    s0 += v4; q0 = fmaf(v4, v4, q0);
    s1 += v5; q1 = fmaf(v5, v5, q1);
    s2 += v6; q2 = fmaf(v6, v6, q2);
    s3 += v7; q3 = fmaf(v7, v7, q3);
  }
  for (; r < r1; ++r) {
    float v = xc[(size_t)r * DD];
    s0 += v; q0 = fmaf(v, v, q0);
  }
  atomicAdd(&csum[col], (s0 + s1) + (s2 + s3));
  atomicAdd(&csq[col], (q0 + q1) + (q2 + q3));
}

__global__ void k_finalize_stats(const float* __restrict__ csum, const float* __restrict__ csq,
                                 float* __restrict__ mean, float* __restrict__ rstd, int n) {
  int j = threadIdx.x;
  float s = csum[j], q = csq[j];
  float m = s / (float)n;
  float var = (q - s * m) / (float)(n - 1);   // unbiased, ddof=1
  mean[j] = m;
  rstd[j] = 1.0f / sqrtf(var);
}

// standardize and cast to bf16
__global__ void k_standardize(const float* __restrict__ x, const float* __restrict__ mean,
                              const float* __restrict__ rstd, u16* __restrict__ xs, int total4) {
  int i = blockIdx.x * blockDim.x + threadIdx.x;
  if (i >= total4) return;
  int c4 = i & (DD / 4 - 1);
  float4 v = ((const float4*)x)[i];
  float4 m = ((const float4*)mean)[c4];
  float4 r = ((const float4*)rstd)[c4];
  uint2 o;
  o.x = (uint)f2bf((v.x - m.x) * r.x) | ((uint)f2bf((v.y - m.y) * r.y) << 16);
  o.y = (uint)f2bf((v.z - m.z) * r.z) | ((uint)f2bf((v.w - m.w) * r.w) << 16);
  ((uint2*)xs)[i] = o;
}

// ---------------- weight fp32 [K][N] -> bf16 transposed [N][K] ----------------
__global__ void k_convWt(const float* __restrict__ W, u16* __restrict__ Wt, int K, int N) {
  int k = blockIdx.x;
  for (int nn = threadIdx.x; nn < N; nn += blockDim.x)
    Wt[(size_t)nn * K + k] = f2bf(W[(size_t)k * N + nn]);
}

// ---------------- CSR build (by destination, self-loop appended per row) ----------------
__global__ void k_count_deg(const int* __restrict__ edst, int E, int* __restrict__ degi) {
  int i = blockIdx.x * blockDim.x + threadIdx.x;
  if (i < E) atomicAdd(&degi[edst[i]], 1);
}

// per-chunk sums of (deg+1)
__global__ __launch_bounds__(256) void k_blocksum(const int* __restrict__ degi, int* __restrict__ bsum, int n) {
  int b = blockIdx.x, tid = threadIdx.x;
  int base = b * SCHUNK;
  int end = min(base + SCHUNK, n);
  int s = 0;
  for (int i = base + tid; i < end; i += 256) s += degi[i] + 1;
  __shared__ int ws[4];
  #pragma unroll
  for (int off = 32; off >= 1; off >>= 1) s += __shfl_down(s, off);
  if ((tid & 63) == 0) ws[tid >> 6] = s;
  __syncthreads();
  if (tid == 0) bsum[b] = ws[0] + ws[1] + ws[2] + ws[3];
}

// exclusive scan of <=64 block sums, one wave
__global__ void k_scan_bsums(int* __restrict__ bsum, int nb) {
  int lane = threadIdx.x;  // 64 threads
  int orig = (lane < nb) ? bsum[lane] : 0;
  int v = orig;
  #pragma unroll
  for (int off = 1; off < 64; off <<= 1) {
    int t = __shfl_up(v, off);
    if (lane >= off) v += t;
  }
  if (lane < nb) bsum[lane] = v - orig;  // exclusive
}

// chunk-local scan + global offset -> rowptr, cursor, dinv
__global__ __launch_bounds__(256) void k_rowptr_write(const int* __restrict__ degi, const int* __restrict__ bsum,
                                                      int* __restrict__ rowptr, int* __restrict__ cursor,
                                                      float* __restrict__ dinv, int n) {
  int b = blockIdx.x, tid = threadIdx.x;
  int base = b * SCHUNK + tid * 4;
  int d[4];
  int t = 0;
  #pragma unroll
  for (int j = 0; j < 4; ++j) {
    int i = base + j;
    d[j] = (i < n) ? degi[i] + 1 : 0;
    t += d[j];
  }
  __shared__ int sc[256];
  sc[tid] = t;
  __syncthreads();
  for (int off = 1; off < 256; off <<= 1) {
    int v = 0;
    if (tid >= off) v = sc[tid - off];
    __syncthreads();
    if (tid >= off) sc[tid] += v;
    __syncthreads();
  }
  int run = bsum[b] + sc[tid] - t;
  #pragma unroll
  for (int j = 0; j < 4; ++j) {
    int i = base + j;
    if (i < n) {
      rowptr[i] = run;
      cursor[i] = run;
      dinv[i] = rsqrtf((float)d[j]);
      run += d[j];
      if (i == n - 1) rowptr[n] = run;
    }
  }
}

__global__ void k_scatter(const int* __restrict__ esrc, const int* __restrict__ edst, int E,
                          int* __restrict__ cursor, int* __restrict__ csrsrc) {
  int i = blockIdx.x * blockDim.x + threadIdx.x;
  if (i < E) {
    int d = edst[i];
    int p = atomicAdd(&cursor[d], 1);
    csrsrc[p] = esrc[i];
  }
}

__global__ void k_selfloop(const int* __restrict__ rowptr, int* __restrict__ csrsrc, int n) {
  int i = blockIdx.x * blockDim.x + threadIdx.x;
  if (i < n) csrsrc[rowptr[i + 1] - 1] = i;
}

// ---------------- bf16 MFMA GEMM, 128x128 tile (N multiple of 128): C = A @ Bt^T ----------------
__global__ __launch_bounds__(256) void k_mfma_gemm128(const u16* __restrict__ A, const u16* __restrict__ Bt,
                                                      u16* __restrict__ C, int M, int N, int K,
                                                      const float* __restrict__ rowScale) {
  __shared__ u16 As[128 * 40];  // [128][32+8] pad -> 2-way (free) LDS banking
  __shared__ u16 Bs[128 * 40];
  int tid = threadIdx.x;
  int wave = tid >> 6, lane = tid & 63, quad = lane >> 4, l16 = lane & 15;
  int rowBase = blockIdx.y * 128, colBase = blockIdx.x * 128;
  f32x4 acc[2][8] = {};
  for (int k0 = 0; k0 < K; k0 += 32) {
    #pragma unroll
    for (int i = 0; i < 2; ++i) {
      int ch = tid + i * 256;
      int r = ch >> 2, cc = (ch & 3) * 8;
      int gr = min(rowBase + r, M - 1);  // clamp: junk rows never stored
      *(uint4*)&As[r * 40 + cc] = *(const uint4*)(A + (size_t)gr * K + k0 + cc);
      *(uint4*)&Bs[r * 40 + cc] = *(const uint4*)(Bt + (size_t)(colBase + r) * K + k0 + cc);
    }
    __syncthreads();
    short8 af0 = *(const short8*)&As[(wave * 32 + l16) * 40 + quad * 8];
    short8 af1 = *(const short8*)&As[(wave * 32 + 16 + l16) * 40 + quad * 8];
    #pragma unroll
    for (int j = 0; j < 8; ++j) {
      short8 bf = *(const short8*)&Bs[(j * 16 + l16) * 40 + quad * 8];
      acc[0][j] = __builtin_amdgcn_mfma_f32_16x16x32_bf16(af0, bf, acc[0][j], 0, 0, 0);
      acc[1][j] = __builtin_amdgcn_mfma_f32_16x16x32_bf16(af1, bf, acc[1][j], 0, 0, 0);
    }
    __syncthreads();
  }
  // C/D layout: col=lane&15, row=quad*4+reg
  #pragma unroll
  for (int i = 0; i < 2; ++i) {
    #pragma unroll
    for (int r = 0; r < 4; ++r) {
      int gr = rowBase + wave * 32 + i * 16 + quad * 4 + r;
      if (gr >= M) continue;
      float sc = rowScale ? rowScale[gr] : 1.0f;
      #pragma unroll
      for (int j = 0; j < 8; ++j) {
        int gc = colBase + j * 16 + l16;
        C[(size_t)gr * N + gc] = f2bf(acc[i][j][r] * sc);
      }
    }
  }
}

// ---------------- bf16 MFMA GEMM, 128x64 tile (generic N, used for final W2) ----------------
__global__ __launch_bounds__(256) void k_mfma_gemm(const u16* __restrict__ A, const u16* __restrict__ Bt,
                                                   u16* __restrict__ C, int M, int N, int K,
                                                   const float* __restrict__ rowScale) {
  __shared__ u16 As[128 * 40];
  __shared__ u16 Bs[64 * 40];
  int tid = threadIdx.x;
  int wave = tid >> 6, lane = tid & 63, quad = lane >> 4, l16 = lane & 15;
  int rowBase = blockIdx.y * 128, colBase = blockIdx.x * 64;
  f32x4 acc[2][4] = {};
  for (int k0 = 0; k0 < K; k0 += 32) {
    #pragma unroll
    for (int i = 0; i < 2; ++i) {
      int ch = tid + i * 256;
      int r = ch >> 2, cc = (ch & 3) * 8;
      int gr = rowBase + r;
      uint4 v = make_uint4(0, 0, 0, 0);
      if (gr < M) v = *(const uint4*)(A + (size_t)gr * K + k0 + cc);
      *(uint4*)&As[r * 40 + cc] = v;
    }
    {
      int r = tid >> 2, cc = (tid & 3) * 8;
      int gn = colBase + r;
      uint4 v = make_uint4(0, 0, 0, 0);
      if (gn < N) v = *(const uint4*)(Bt + (size_t)gn * K + k0 + cc);
      *(uint4*)&Bs[r * 40 + cc] = v;
    }
    __syncthreads();
    short8 af[2];
    af[0] = *(const short8*)&As[(wave * 32 + l16) * 40 + quad * 8];
    af[1] = *(const short8*)&As[(wave * 32 + 16 + l16) * 40 + quad * 8];
    short8 bf[4];
    #pragma unroll
    for (int j = 0; j < 4; ++j) bf[j] = *(const short8*)&Bs[(j * 16 + l16) * 40 + quad * 8];
    #pragma unroll
    for (int i = 0; i < 2; ++i)
      #pragma unroll
      for (int j = 0; j < 4; ++j)
        acc[i][j] = __builtin_amdgcn_mfma_f32_16x16x32_bf16(af[i], bf[j], acc[i][j], 0, 0, 0);
    __syncthreads();
  }
  #pragma unroll
  for (int i = 0; i < 2; ++i) {
    #pragma unroll
    for (int r = 0; r < 4; ++r) {
      int gr = rowBase + wave * 32 + i * 16 + quad * 4 + r;
      if (gr >= M) continue;
      float sc = rowScale ? rowScale[gr] : 1.0f;
      #pragma unroll
      for (int j = 0; j < 4; ++j) {
        int gc = colBase + j * 16 + l16;
        if (gc < N) C[(size_t)gr * N + gc] = f2bf(acc[i][j][r] * sc);
      }
    }
  }
}

// ---------------- GCN aggregate (rows pre-scaled by dinv[s]): out[d]=relu(dinv[d]*sum + b) ----------------
__global__ __launch_bounds__(256) void k_gcn_agg(const u16* __restrict__ hs, const int* __restrict__ rowptr,
                                                 const int* __restrict__ csrsrc, const float* __restrict__ dinv,
                                                 const float* __restrict__ bias, u16* __restrict__ out, int n) {
  int wave = (blockIdx.x * blockDim.x + threadIdx.x) >> 6;
  int lane = threadIdx.x & 63;
  int sub = lane >> 5, l = lane & 31;
  int w = wave * 2 + sub;
  if (w >= n) return;
  int p0 = rowptr[w], p1 = rowptr[w + 1];
  float a[8] = {};
  int p = p0;
  for (; p + 4 <= p1; p += 4) {
    int s0 = csrsrc[p], s1 = csrsrc[p + 1], s2 = csrsrc[p + 2], s3 = csrsrc[p + 3];
    uint4 v0 = *(const uint4*)(hs + (size_t)s0 * DD + l * 8);
    uint4 v1 = *(const uint4*)(hs + (size_t)s1 * DD + l * 8);
    uint4 v2 = *(const uint4*)(hs + (size_t)s2 * DD + l * 8);
    uint4 v3 = *(const uint4*)(hs + (size_t)s3 * DD + l * 8);
    acc8(a, v0); acc8(a, v1); acc8(a, v2); acc8(a, v3);
  }
  for (; p < p1; ++p) {
    int s = csrsrc[p];
    uint4 v = *(const uint4*)(hs + (size_t)s * DD + l * 8);
    acc8(a, v);
  }
  float dd = dinv[w];
  float4 b0 = ((const float4*)bias)[l * 2];
  float4 b1 = ((const float4*)bias)[l * 2 + 1];
  float r0 = fmaxf(dd * a[0] + b0.x, 0.f), r1 = fmaxf(dd * a[1] + b0.y, 0.f);
  float r2 = fmaxf(dd * a[2] + b0.z, 0.f), r3 = fmaxf(dd * a[3] + b0.w, 0.f);
  float r4 = fmaxf(dd * a[4] + b1.x, 0.f), r5 = fmaxf(dd * a[5] + b1.y, 0.f);
  float r6 = fmaxf(dd * a[6] + b1.z, 0.f), r7 = fmaxf(dd * a[7] + b1.w, 0.f);
  uint4 o;
  o.x = (uint)f2bf(r0) | ((uint)f2bf(r1) << 16);
  o.y = (uint)f2bf(r2) | ((uint)f2bf(r3) << 16);
  o.z = (uint)f2bf(r4) | ((uint)f2bf(r5) << 16);
  o.w = (uint)f2bf(r6) | ((uint)f2bf(r7) << 16);
  *(uint4*)(out + (size_t)w * DD + l * 8) = o;
}

// ---------------- GAT: per-node attention logits al = h . a ----------------
__global__ __launch_bounds__(256) void k_al(const u16* __restrict__ h, const float* __restrict__ va,
                                            const float* __restrict__ vb, float* __restrict__ als,
                                            float* __restrict__ ald, int n) {
  int w = (blockIdx.x * blockDim.x + threadIdx.x) >> 6;
  int lane = threadIdx.x & 63;
  if (w >= n) return;
  uint2 v = *(const uint2*)(h + (size_t)w * DD + lane * 4);
  float x0 = __uint_as_float(v.x << 16), x1 = __uint_as_float(v.x & 0xffff0000u);
  float x2 = __uint_as_float(v.y << 16), x3 = __uint_as_float(v.y & 0xffff0000u);
  float4 a = ((const float4*)va)[lane];
  float4 b = ((const float4*)vb)[lane];
  float s1 = x0 * a.x + x1 * a.y + x2 * a.z + x3 * a.w;
  float s2 = x0 * b.x + x1 * b.y + x2 * b.z + x3 * b.w;
  #pragma unroll
  for (int off = 1; off < 64; off <<= 1) {
    s1 += __shfl_xor(s1, off);
    s2 += __shfl_xor(s2, off);
  }
  if (lane == 0) { als[w] = s1; ald[w] = s2; }
}

// ---------------- GAT aggregate: online segment softmax + weighted sum + bias + relu ----------------
__global__ __launch_bounds__(256) void k_gat_agg(const u16* __restrict__ h, const int* __restrict__ rowptr,
                                                 const int* __restrict__ csrsrc, const float* __restrict__ als,
                                                 const float* __restrict__ ald, const float* __restrict__ bias,
                                                 u16* __restrict__ out, int n) {
  int wave = (blockIdx.x * blockDim.x + threadIdx.x) >> 6;
  int lane = threadIdx.x & 63;
  int sub = lane >> 5, l = lane & 31;
  int w = wave * 2 + sub;
  if (w >= n) return;
  float ad = ald[w];
  int p0 = rowptr[w], p1 = rowptr[w + 1];
  // pass 1: online softmax stats, lanes stride edges within half-wave
  float m = -1e30f, z = 0.f;
  for (int p = p0 + l; p < p1; p += 32) {
    float e = als[csrsrc[p]] + ad;
    e = (e > 0.f) ? e : NSLOPE * e;
    if (e > m) { z = z * __expf(m - e) + 1.f; m = e; }
    else z += __expf(e - m);
  }
  #pragma unroll
  for (int off = 16; off >= 1; off >>= 1) {
    float m2 = __shfl_xor(m, off), z2 = __shfl_xor(z, off);
    float M = fmaxf(m, m2);
    z = z * __expf(m - M) + z2 * __expf(m2 - M);
    m = M;
  }
  float invz = 1.0f / z;
  // pass 2: weighted feature accumulation, lane owns 8 features, unroll x4
  float a[8] = {};
  int p = p0;
  for (; p + 4 <= p1; p += 4) {
    int s0 = csrsrc[p], s1 = csrsrc[p + 1], s2 = csrsrc[p + 2], s3 = csrsrc[p + 3];
    float e0 = als[s0] + ad; e0 = (e0 > 0.f) ? e0 : NSLOPE * e0;
    float e1 = als[s1] + ad; e1 = (e1 > 0.f) ? e1 : NSLOPE * e1;
    float e2 = als[s2] + ad; e2 = (e2 > 0.f) ? e2 : NSLOPE * e2;
    float e3 = als[s3] + ad; e3 = (e3 > 0.f) ? e3 : NSLOPE * e3;
    uint4 v0 = *(const uint4*)(h + (size_t)s0 * DD + l * 8);
    uint4 v1 = *(const uint4*)(h + (size_t)s1 * DD + l * 8);
    uint4 v2 = *(const uint4*)(h + (size_t)s2 * DD + l * 8);
    uint4 v3 = *(const uint4*)(h + (size_t)s3 * DD + l * 8);
    wacc8(a, v0, __expf(e0 - m) * invz);
    wacc8(a, v1, __expf(e1 - m) * invz);
    wacc8(a, v2, __expf(e2 - m) * invz);
    wacc8(a, v3, __expf(e3 - m) * invz);
  }
  for (; p < p1; ++p) {
    int s = csrsrc[p];
    float e = als[s] + ad; e = (e > 0.f) ? e : NSLOPE * e;
    uint4 v = *(const uint4*)(h + (size_t)s * DD + l * 8);
    wacc8(a, v, __expf(e - m) * invz);
  }
  float4 b0 = ((const float4*)bias)[l * 2];
  float4 b1 = ((const float4*)bias)[l * 2 + 1];
  float r0 = fmaxf(a[0] + b0.x, 0.f), r1 = fmaxf(a[1] + b0.y, 0.f);
  float r2 = fmaxf(a[2] + b0.z, 0.f), r3 = fmaxf(a[3] + b0.w, 0.f);
  float r4 = fmaxf(a[4] + b1.x, 0.f), r5 = fmaxf(a[5] + b1.y, 0.f);
  float r6 = fmaxf(a[6] + b1.z, 0.f), r7 = fmaxf(a[7] + b1.w, 0.f);
  uint4 o;
  o.x = (uint)f2bf(r0) | ((uint)f2bf(r1) << 16);
  o.y = (uint)f2bf(r2) | ((uint)f2bf(r3) << 16);
  o.z = (uint)f2bf(r4) | ((uint)f2bf(r5) << 16);
  o.w = (uint)f2bf(r6) | ((uint)f2bf(r7) << 16);
  *(uint4*)(out + (size_t)w * DD + l * 8) = o;
}

// ---------------- final GCN (H->40, rows pre-scaled by dinv) + log_softmax, fp32 out ----------------
__global__ __launch_bounds__(256) void k_gcn2_lsm(const u16* __restrict__ hs, const int* __restrict__ rowptr,
                                                  const int* __restrict__ csrsrc, const float* __restrict__ dinv,
                                                  const float* __restrict__ bias, float* __restrict__ out, int n) {
  int w = (blockIdx.x * blockDim.x + threadIdx.x) >> 6;
  int lane = threadIdx.x & 63;
  if (w >= n) return;
  int p0 = rowptr[w], p1 = rowptr[w + 1];
  float acc = 0.f;
  int p = p0;
  for (; p + 4 <= p1; p += 4) {
    int s0 = csrsrc[p], s1 = csrsrc[p + 1], s2 = csrsrc[p + 2], s3 = csrsrc[p + 3];
    if (lane < LL) {
      float v0 = bf2f(hs[(size_t)s0 * LL + lane]);
      float v1 = bf2f(hs[(size_t)s1 * LL + lane]);
      float v2 = bf2f(hs[(size_t)s2 * LL + lane]);
      float v3 = bf2f(hs[(size_t)s3 * LL + lane]);
      acc += v0 + v1 + v2 + v3;
    }
  }
  for (; p < p1; ++p) {
    int s = csrsrc[p];
    if (lane < LL) acc += bf2f(hs[(size_t)s * LL + lane]);
  }
  float dd = dinv[w];
  float v = (lane < LL) ? dd * acc + bias[lane] : -INFINITY;
  float m = v;
  #pragma unroll
  for (int off = 1; off < 64; off <<= 1) m = fmaxf(m, __shfl_xor(m, off));
  float ex = (lane < LL) ? __expf(v - m) : 0.f;
  float z = ex;
  #pragma unroll
  for (int off = 1; off < 64; off <<= 1) z += __shfl_xor(z, off);
  if (lane < LL) out[(size_t)w * LL + lane] = v - m - logf(z);
}

// ---------------- launch ----------------
extern "C" void kernel_launch(void* const* d_in, const int* in_sizes, int n_in,
                              void* d_out, int out_size, void* d_ws, size_t ws_size,
                              hipStream_t stream) {
  const float* x   = (const float*)d_in[0];
  const int*   ei  = (const int*)d_in[1];
  const float* W1  = (const float*)d_in[2];
  const float* b1  = (const float*)d_in[3];
  const float* Wg  = (const float*)d_in[4];
  const float* a_s = (const float*)d_in[5];
  const float* a_d = (const float*)d_in[6];
  const float* bg  = (const float*)d_in[7];
  const float* W2  = (const float*)d_in[8];
  const float* b2  = (const float*)d_in[9];
  float* out = (float*)d_out;

  const int n = in_sizes[0] / DD;
  const int E = in_sizes[1] / 2;
  const int M = E + n;
  const int* esrc = ei;
  const int* edst = ei + E;

  char* wp = (char*)d_ws;
  auto carve = [&](size_t bytes) -> char* {
    char* p = wp;
    wp += (bytes + 255) & ~(size_t)255;
    return p;
  };
  u16*   buf0   = (u16*)carve((size_t)n * DD * 2);
  u16*   buf1   = (u16*)carve((size_t)n * DD * 2);
  u16*   h40    = (u16*)carve((size_t)n * LL * 2);
  u16*   W1t    = (u16*)carve((size_t)DD * DD * 2);
  u16*   Wgt    = (u16*)carve((size_t)DD * DD * 2);
  u16*   W2t    = (u16*)carve((size_t)LL * DD * 2);
  int*   csrsrc = (int*)carve((size_t)M * 4);
  int*   rowptr = (int*)carve((size_t)(n + 1) * 4);
  int*   cursor = (int*)carve((size_t)n * 4);
  int*   degi   = (int*)carve((size_t)n * 4);
  int*   bsum   = (int*)carve(64 * 4);
  float* dinv   = (float*)carve((size_t)n * 4);
  float* alsA   = (float*)carve((size_t)n * 4);
  float* aldA   = (float*)carve((size_t)n * 4);
  float* csum   = (float*)carve(DD * 4);
  float* csq    = (float*)carve(DD * 4);
  float* mean   = (float*)carve(DD * 4);
  float* rstd   = (float*)carve(DD * 4);

  hipMemsetAsync(degi, 0, (size_t)n * 4, stream);
  hipMemsetAsync(csum, 0, DD * 4, stream);
  hipMemsetAsync(csq, 0, DD * 4, stream);

  // standardization -> bf16 buf0
  const int rowsPerBlk = 32;  // ~1563 blocks: many waves, 8 independent loads each (R8 lesson)
  k_colstats<<<(n + rowsPerBlk - 1) / rowsPerBlk, DD, 0, stream>>>(x, csum, csq, n, rowsPerBlk);
  k_finalize_stats<<<1, DD, 0, stream>>>(csum, csq, mean, rstd, n);
  int total4 = n * (DD / 4);
  k_standardize<<<(total4 + 255) / 256, 256, 0, stream>>>(x, mean, rstd, buf0, total4);

  // weight convert+transpose to bf16
  k_convWt<<<DD, 256, 0, stream>>>(W1, W1t, DD, DD);
  k_convWt<<<DD, 256, 0, stream>>>(Wg, Wgt, DD, DD);
  k_convWt<<<DD, 64, 0, stream>>>(W2, W2t, DD, LL);

  // CSR build — parallel hierarchical scan
  int nb = (n + SCHUNK - 1) / SCHUNK;
  k_count_deg<<<(E + 255) / 256, 256, 0, stream>>>(edst, E, degi);
  k_blocksum<<<nb, 256, 0, stream>>>(degi, bsum, n);
  k_scan_bsums<<<1, 64, 0, stream>>>(bsum, nb);
  k_rowptr_write<<<nb, 256, 0, stream>>>(degi, bsum, rowptr, cursor, dinv, n);
  k_scatter<<<(E + 255) / 256, 256, 0, stream>>>(esrc, edst, E, cursor, csrsrc);
  k_selfloop<<<(n + 255) / 256, 256, 0, stream>>>(rowptr, csrsrc, n);

  dim3 blk(256);
  dim3 gemmGrid(DD / 128, (n + 127) / 128);   // 128x128 tiles for square GEMMs
  int aggGrid1 = (n + 3) / 4;   // 1 wave per node kernels (k_al, k_gcn2_lsm)
  int aggGrid2 = (n + 7) / 8;   // 2 nodes per wave kernels

  // layer 1: GCN(256->256) + relu  (GEMM epilogue pre-scales rows by dinv)
  k_mfma_gemm128<<<gemmGrid, blk, 0, stream>>>(buf0, W1t, buf1, n, DD, DD, dinv);
  k_gcn_agg<<<aggGrid2, blk, 0, stream>>>(buf1, rowptr, csrsrc, dinv, b1, buf0, n);

  // layers 2,3: GAT(256->256) + relu
  for (int l = 0; l < 2; ++l) {
    k_mfma_gemm128<<<gemmGrid, blk, 0, stream>>>(buf0, Wgt, buf1, n, DD, DD, nullptr);
    k_al<<<aggGrid1, blk, 0, stream>>>(buf1, a_s, a_d, alsA, aldA, n);
    k_gat_agg<<<aggGrid2, blk, 0, stream>>>(buf1, rowptr, csrsrc, alsA, aldA, bg, buf0, n);
  }

  // final: GCN(256->40) + log_softmax (rows pre-scaled by dinv)
  dim3 gemmGrid2(1, (n + 127) / 128);
  k_mfma_gemm<<<gemmGrid2, blk, 0, stream>>>(buf0, W2t, h40, n, LL, DD, dinv);
  k_gcn2_lsm<<<aggGrid1, blk, 0, stream>>>(h40, rowptr, csrsrc, dinv, b2, out, n);
}

// Round 10
// 556.634 us; speedup vs baseline: 1.0971x; 1.0203x over previous
//
#include <hip/hip_runtime.h>
#include <math.h>

#define DD 256      // input/hidden feature dim
#define LL 40       // output classes
#define NSLOPE 0.2f // PyG GATConv leaky_relu slope
#define SCHUNK 1024 // elements per scan block (n<=64*SCHUNK)

typedef unsigned short u16;
typedef unsigned int uint;
typedef __attribute__((ext_vector_type(8))) short short8;
typedef __attribute__((ext_vector_type(4))) float f32x4;

__device__ __forceinline__ float bf2f(u16 v) { return __uint_as_float(((uint)v) << 16); }
__device__ __forceinline__ u16 f2bf(float f) {
  uint u = __float_as_uint(f);
  return (u16)((u + 0x7fff + ((u >> 16) & 1)) >> 16);  // RNE
}
__device__ __forceinline__ void acc8(float* a, uint4 v) {
  a[0] += __uint_as_float(v.x << 16);
  a[1] += __uint_as_float(v.x & 0xffff0000u);
  a[2] += __uint_as_float(v.y << 16);
  a[3] += __uint_as_float(v.y & 0xffff0000u);
  a[4] += __uint_as_float(v.z << 16);
  a[5] += __uint_as_float(v.z & 0xffff0000u);
  a[6] += __uint_as_float(v.w << 16);
  a[7] += __uint_as_float(v.w & 0xffff0000u);
}
__device__ __forceinline__ void wacc8(float* a, uint4 v, float w) {
  a[0] += w * __uint_as_float(v.x << 16);
  a[1] += w * __uint_as_float(v.x & 0xffff0000u);
  a[2] += w * __uint_as_float(v.y << 16);
  a[3] += w * __uint_as_float(v.y & 0xffff0000u);
  a[4] += w * __uint_as_float(v.z << 16);
  a[5] += w * __uint_as_float(v.z & 0xffff0000u);
  a[6] += w * __uint_as_float(v.w << 16);
  a[7] += w * __uint_as_float(v.w & 0xffff0000u);
}

// ================= fused preprocessing stage 1: colstats | count_deg | convWt x3 =================
__global__ __launch_bounds__(256) void k_pre1(const float* __restrict__ x, float* __restrict__ csum,
                                              float* __restrict__ csq, int n, int rowsPerBlk, int nbC,
                                              const int* __restrict__ edst, int E, int* __restrict__ degi, int nbE,
                                              const float* __restrict__ W1, u16* __restrict__ W1t,
                                              const float* __restrict__ Wg, u16* __restrict__ Wgt,
                                              const float* __restrict__ W2, u16* __restrict__ W2t) {
  int b = blockIdx.x;
  int tid = threadIdx.x;
  if (b < nbC) {
    // ---- column stats: thread = column, 8 explicit independent loads (R9-proven shape) ----
    int r0 = b * rowsPerBlk;
    int r1 = min(r0 + rowsPerBlk, n);
    float s0 = 0.f, s1 = 0.f, s2 = 0.f, s3 = 0.f;
    float q0 = 0.f, q1 = 0.f, q2 = 0.f, q3 = 0.f;
    const float* xc = x + tid;
    int r = r0;
    for (; r + 8 <= r1; r += 8) {
      float v0 = xc[(size_t)(r + 0) * DD];
      float v1 = xc[(size_t)(r + 1) * DD];
      float v2 = xc[(size_t)(r + 2) * DD];
      float v3 = xc[(size_t)(r + 3) * DD];
      float v4 = xc[(size_t)(r + 4) * DD];
      float v5 = xc[(size_t)(r + 5) * DD];
      float v6 = xc[(size_t)(r + 6) * DD];
      float v7 = xc[(size_t)(r + 7) * DD];
      s0 += v0; q0 = fmaf(v0, v0, q0);
      s1 += v1; q1 = fmaf(v1, v1, q1);
      s2 += v2; q2 = fmaf(v2, v2, q2);
      s3 += v3; q3 = fmaf(v3, v3, q3);
      s0 += v4; q0 = fmaf(v4, v4, q0);
      s1 += v5; q1 = fmaf(v5, v5, q1);
      s2 += v6; q2 = fmaf(v6, v6, q2);
      s3 += v7; q3 = fmaf(v7, v7, q3);
    }
    for (; r < r1; ++r) {
      float v = xc[(size_t)r * DD];
      s0 += v; q0 = fmaf(v, v, q0);
    }
    atomicAdd(&csum[tid], (s0 + s1) + (s2 + s3));
    atomicAdd(&csq[tid], (q0 + q1) + (q2 + q3));
  } else if (b < nbC + nbE) {
    int i = (b - nbC) * 256 + tid;
    if (i < E) atomicAdd(&degi[edst[i]], 1);
  } else {
    int b2 = b - nbC - nbE;  // [0, 3*DD): weight convert+transpose
    if (b2 < DD) {
      int k = b2;
      for (int nn = tid; nn < DD; nn += 256) W1t[(size_t)nn * DD + k] = f2bf(W1[(size_t)k * DD + nn]);
    } else if (b2 < 2 * DD) {
      int k = b2 - DD;
      for (int nn = tid; nn < DD; nn += 256) Wgt[(size_t)nn * DD + k] = f2bf(Wg[(size_t)k * DD + nn]);
    } else {
      int k = b2 - 2 * DD;
      for (int nn = tid; nn < LL; nn += 256) W2t[(size_t)nn * DD + k] = f2bf(W2[(size_t)k * LL + nn]);
    }
  }
}

// ================= fused stage 2: finalize_stats | blocksum =================
__global__ __launch_bounds__(256) void k_pre2(const float* __restrict__ csum, const float* __restrict__ csq,
                                              float* __restrict__ mean, float* __restrict__ rstd, int n,
                                              const int* __restrict__ degi, int* __restrict__ bsum, int nb) {
  int b = blockIdx.x;
  int tid = threadIdx.x;
  if (b == nb) {
    float s = csum[tid], q = csq[tid];
    float m = s / (float)n;
    float var = (q - s * m) / (float)(n - 1);   // unbiased, ddof=1
    mean[tid] = m;
    rstd[tid] = 1.0f / sqrtf(var);
  } else {
    int base = b * SCHUNK;
    int end = min(base + SCHUNK, n);
    int s = 0;
    for (int i = base + tid; i < end; i += 256) s += degi[i] + 1;
    __shared__ int ws[4];
    #pragma unroll
    for (int off = 32; off >= 1; off >>= 1) s += __shfl_down(s, off);
    if ((tid & 63) == 0) ws[tid >> 6] = s;
    __syncthreads();
    if (tid == 0) bsum[b] = ws[0] + ws[1] + ws[2] + ws[3];
  }
}

// exclusive scan of <=64 block sums, one wave
__global__ void k_scan_bsums(int* __restrict__ bsum, int nb) {
  int lane = threadIdx.x;  // 64 threads
  int orig = (lane < nb) ? bsum[lane] : 0;
  int v = orig;
  #pragma unroll
  for (int off = 1; off < 64; off <<= 1) {
    int t = __shfl_up(v, off);
    if (lane >= off) v += t;
  }
  if (lane < nb) bsum[lane] = v - orig;  // exclusive
}

// ================= fused stage 4: standardize | rowptr_write(+selfloop first) =================
__global__ __launch_bounds__(256) void k_pre4(const float* __restrict__ x, const float* __restrict__ mean,
                                              const float* __restrict__ rstd, u16* __restrict__ xs,
                                              int total4, int nbS,
                                              const int* __restrict__ degi, const int* __restrict__ bsum,
                                              int* __restrict__ rowptr, int* __restrict__ cursor,
                                              int* __restrict__ csrsrc, float* __restrict__ dinv, int n) {
  int b = blockIdx.x;
  int tid = threadIdx.x;
  if (b < nbS) {
    int i = b * 256 + tid;
    if (i >= total4) return;
    int c4 = i & (DD / 4 - 1);
    float4 v = ((const float4*)x)[i];
    float4 m = ((const float4*)mean)[c4];
    float4 r = ((const float4*)rstd)[c4];
    uint2 o;
    o.x = (uint)f2bf((v.x - m.x) * r.x) | ((uint)f2bf((v.y - m.y) * r.y) << 16);
    o.y = (uint)f2bf((v.z - m.z) * r.z) | ((uint)f2bf((v.w - m.w) * r.w) << 16);
    ((uint2*)xs)[i] = o;
  } else {
    int bb = b - nbS;
    int base = bb * SCHUNK + tid * 4;
    int d[4];
    int t = 0;
    #pragma unroll
    for (int j = 0; j < 4; ++j) {
      int i = base + j;
      d[j] = (i < n) ? degi[i] + 1 : 0;
      t += d[j];
    }
    __shared__ int sc[256];
    sc[tid] = t;
    __syncthreads();
    for (int off = 1; off < 256; off <<= 1) {
      int v = 0;
      if (tid >= off) v = sc[tid - off];
      __syncthreads();
      if (tid >= off) sc[tid] += v;
      __syncthreads();
    }
    int run = bsum[bb] + sc[tid] - t;
    #pragma unroll
    for (int j = 0; j < 4; ++j) {
      int i = base + j;
      if (i < n) {
        rowptr[i] = run;
        csrsrc[run] = i;       // self-loop occupies slot 0 of each row
        cursor[i] = run + 1;   // edges fill after it
        dinv[i] = rsqrtf((float)d[j]);
        run += d[j];
        if (i == n - 1) rowptr[n] = run;
      }
    }
  }
}

__global__ void k_scatter(const int* __restrict__ esrc, const int* __restrict__ edst, int E,
                          int* __restrict__ cursor, int* __restrict__ csrsrc) {
  int i = blockIdx.x * blockDim.x + threadIdx.x;
  if (i < E) {
    int d = edst[i];
    int p = atomicAdd(&cursor[d], 1);
    csrsrc[p] = esrc[i];
  }
}

// ---------------- bf16 MFMA GEMM, 128x128 tile; optional row scale; optional fused attention logits ----------------
// If aS: als[row] += acc_row . aS (this block's 128-col slice), likewise ald/aD (atomic, buffers pre-zeroed).
__global__ __launch_bounds__(256) void k_mfma_gemm128(const u16* __restrict__ A, const u16* __restrict__ Bt,
                                                      u16* __restrict__ C, int M, int N, int K,
                                                      const float* __restrict__ rowScale,
                                                      const float* __restrict__ aS, const float* __restrict__ aD,
                                                      float* __restrict__ als, float* __restrict__ ald) {
  __shared__ u16 As[128 * 40];  // [128][32+8] pad -> 2-way (free) LDS banking
  __shared__ u16 Bs[128 * 40];
  int tid = threadIdx.x;
  int wave = tid >> 6, lane = tid & 63, quad = lane >> 4, l16 = lane & 15;
  int rowBase = blockIdx.y * 128, colBase = blockIdx.x * 128;
  f32x4 acc[2][8] = {};
  for (int k0 = 0; k0 < K; k0 += 32) {
    #pragma unroll
    for (int i = 0; i < 2; ++i) {
      int ch = tid + i * 256;
      int r = ch >> 2, cc = (ch & 3) * 8;
      int gr = min(rowBase + r, M - 1);  // clamp: junk rows never stored
      *(uint4*)&As[r * 40 + cc] = *(const uint4*)(A + (size_t)gr * K + k0 + cc);
      *(uint4*)&Bs[r * 40 + cc] = *(const uint4*)(Bt + (size_t)(colBase + r) * K + k0 + cc);
    }
    __syncthreads();
    short8 af0 = *(const short8*)&As[(wave * 32 + l16) * 40 + quad * 8];
    short8 af1 = *(const short8*)&As[(wave * 32 + 16 + l16) * 40 + quad * 8];
    #pragma unroll
    for (int j = 0; j < 8; ++j) {
      short8 bf = *(const short8*)&Bs[(j * 16 + l16) * 40 + quad * 8];
      acc[0][j] = __builtin_amdgcn_mfma_f32_16x16x32_bf16(af0, bf, acc[0][j], 0, 0, 0);
      acc[1][j] = __builtin_amdgcn_mfma_f32_16x16x32_bf16(af1, bf, acc[1][j], 0, 0, 0);
    }
    __syncthreads();
  }
  // C/D layout: col=lane&15, row=quad*4+reg
  #pragma unroll
  for (int i = 0; i < 2; ++i) {
    #pragma unroll
    for (int r = 0; r < 4; ++r) {
      int gr = rowBase + wave * 32 + i * 16 + quad * 4 + r;
      if (gr >= M) continue;
      float sc = rowScale ? rowScale[gr] : 1.0f;
      #pragma unroll
      for (int j = 0; j < 8; ++j) {
        int gc = colBase + j * 16 + l16;
        C[(size_t)gr * N + gc] = f2bf(acc[i][j][r] * sc);
      }
      if (aS) {  // fused partial attention logits for this 128-col slice
        float t1 = 0.f, t2 = 0.f;
        #pragma unroll
        for (int j = 0; j < 8; ++j) {
          int gc = colBase + j * 16 + l16;
          float v = acc[i][j][r];
          t1 = fmaf(v, aS[gc], t1);
          t2 = fmaf(v, aD[gc], t2);
        }
        #pragma unroll
        for (int off = 1; off < 16; off <<= 1) {
          t1 += __shfl_xor(t1, off);
          t2 += __shfl_xor(t2, off);
        }
        if (l16 == 0) {
          atomicAdd(&als[gr], t1);
          atomicAdd(&ald[gr], t2);
        }
      }
    }
  }
}

// ---------------- bf16 MFMA GEMM, 128x64 tile (generic N, used for final W2) ----------------
__global__ __launch_bounds__(256) void k_mfma_gemm(const u16* __restrict__ A, const u16* __restrict__ Bt,
                                                   u16* __restrict__ C, int M, int N, int K,
                                                   const float* __restrict__ rowScale) {
  __shared__ u16 As[128 * 40];
  __shared__ u16 Bs[64 * 40];
  int tid = threadIdx.x;
  int wave = tid >> 6, lane = tid & 63, quad = lane >> 4, l16 = lane & 15;
  int rowBase = blockIdx.y * 128, colBase = blockIdx.x * 64;
  f32x4 acc[2][4] = {};
  for (int k0 = 0; k0 < K; k0 += 32) {
    #pragma unroll
    for (int i = 0; i < 2; ++i) {
      int ch = tid + i * 256;
      int r = ch >> 2, cc = (ch & 3) * 8;
      int gr = rowBase + r;
      uint4 v = make_uint4(0, 0, 0, 0);
      if (gr < M) v = *(const uint4*)(A + (size_t)gr * K + k0 + cc);
      *(uint4*)&As[r * 40 + cc] = v;
    }
    {
      int r = tid >> 2, cc = (tid & 3) * 8;
      int gn = colBase + r;
      uint4 v = make_uint4(0, 0, 0, 0);
      if (gn < N) v = *(const uint4*)(Bt + (size_t)gn * K + k0 + cc);
      *(uint4*)&Bs[r * 40 + cc] = v;
    }
    __syncthreads();
    short8 af[2];
    af[0] = *(const short8*)&As[(wave * 32 + l16) * 40 + quad * 8];
    af[1] = *(const short8*)&As[(wave * 32 + 16 + l16) * 40 + quad * 8];
    short8 bf[4];
    #pragma unroll
    for (int j = 0; j < 4; ++j) bf[j] = *(const short8*)&Bs[(j * 16 + l16) * 40 + quad * 8];
    #pragma unroll
    for (int i = 0; i < 2; ++i)
      #pragma unroll
      for (int j = 0; j < 4; ++j)
        acc[i][j] = __builtin_amdgcn_mfma_f32_16x16x32_bf16(af[i], bf[j], acc[i][j], 0, 0, 0);
    __syncthreads();
  }
  #pragma unroll
  for (int i = 0; i < 2; ++i) {
    #pragma unroll
    for (int r = 0; r < 4; ++r) {
      int gr = rowBase + wave * 32 + i * 16 + quad * 4 + r;
      if (gr >= M) continue;
      float sc = rowScale ? rowScale[gr] : 1.0f;
      #pragma unroll
      for (int j = 0; j < 4; ++j) {
        int gc = colBase + j * 16 + l16;
        if (gc < N) C[(size_t)gr * N + gc] = f2bf(acc[i][j][r] * sc);
      }
    }
  }
}

// ---------------- GCN aggregate (rows pre-scaled by dinv[s]): out[d]=relu(dinv[d]*sum + b) ----------------
__global__ __launch_bounds__(256) void k_gcn_agg(const u16* __restrict__ hs, const int* __restrict__ rowptr,
                                                 const int* __restrict__ csrsrc, const float* __restrict__ dinv,
                                                 const float* __restrict__ bias, u16* __restrict__ out, int n) {
  int wave = (blockIdx.x * blockDim.x + threadIdx.x) >> 6;
  int lane = threadIdx.x & 63;
  int sub = lane >> 5, l = lane & 31;
  int w = wave * 2 + sub;
  if (w >= n) return;
  int p0 = rowptr[w], p1 = rowptr[w + 1];
  float a[8] = {};
  int p = p0;
  for (; p + 4 <= p1; p += 4) {
    int s0 = csrsrc[p], s1 = csrsrc[p + 1], s2 = csrsrc[p + 2], s3 = csrsrc[p + 3];
    uint4 v0 = *(const uint4*)(hs + (size_t)s0 * DD + l * 8);
    uint4 v1 = *(const uint4*)(hs + (size_t)s1 * DD + l * 8);
    uint4 v2 = *(const uint4*)(hs + (size_t)s2 * DD + l * 8);
    uint4 v3 = *(const uint4*)(hs + (size_t)s3 * DD + l * 8);
    acc8(a, v0); acc8(a, v1); acc8(a, v2); acc8(a, v3);
  }
  for (; p < p1; ++p) {
    int s = csrsrc[p];
    uint4 v = *(const uint4*)(hs + (size_t)s * DD + l * 8);
    acc8(a, v);
  }
  float dd = dinv[w];
  float4 b0 = ((const float4*)bias)[l * 2];
  float4 b1 = ((const float4*)bias)[l * 2 + 1];
  float r0 = fmaxf(dd * a[0] + b0.x, 0.f), r1 = fmaxf(dd * a[1] + b0.y, 0.f);
  float r2 = fmaxf(dd * a[2] + b0.z, 0.f), r3 = fmaxf(dd * a[3] + b0.w, 0.f);
  float r4 = fmaxf(dd * a[4] + b1.x, 0.f), r5 = fmaxf(dd * a[5] + b1.y, 0.f);
  float r6 = fmaxf(dd * a[6] + b1.z, 0.f), r7 = fmaxf(dd * a[7] + b1.w, 0.f);
  uint4 o;
  o.x = (uint)f2bf(r0) | ((uint)f2bf(r1) << 16);
  o.y = (uint)f2bf(r2) | ((uint)f2bf(r3) << 16);
  o.z = (uint)f2bf(r4) | ((uint)f2bf(r5) << 16);
  o.w = (uint)f2bf(r6) | ((uint)f2bf(r7) << 16);
  *(uint4*)(out + (size_t)w * DD + l * 8) = o;
}

// ---------------- GAT aggregate: online segment softmax + weighted sum + bias + relu ----------------
__global__ __launch_bounds__(256) void k_gat_agg(const u16* __restrict__ h, const int* __restrict__ rowptr,
                                                 const int* __restrict__ csrsrc, const float* __restrict__ als,
                                                 const float* __restrict__ ald, const float* __restrict__ bias,
                                                 u16* __restrict__ out, int n) {
  int wave = (blockIdx.x * blockDim.x + threadIdx.x) >> 6;
  int lane = threadIdx.x & 63;
  int sub = lane >> 5, l = lane & 31;
  int w = wave * 2 + sub;
  if (w >= n) return;
  float ad = ald[w];
  int p0 = rowptr[w], p1 = rowptr[w + 1];
  // pass 1: online softmax stats, lanes stride edges within half-wave
  float m = -1e30f, z = 0.f;
  for (int p = p0 + l; p < p1; p += 32) {
    float e = als[csrsrc[p]] + ad;
    e = (e > 0.f) ? e : NSLOPE * e;
    if (e > m) { z = z * __expf(m - e) + 1.f; m = e; }
    else z += __expf(e - m);
  }
  #pragma unroll
  for (int off = 16; off >= 1; off >>= 1) {
    float m2 = __shfl_xor(m, off), z2 = __shfl_xor(z, off);
    float M = fmaxf(m, m2);
    z = z * __expf(m - M) + z2 * __expf(m2 - M);
    m = M;
  }
  float invz = 1.0f / z;
  // pass 2: weighted feature accumulation, lane owns 8 features, unroll x4
  float a[8] = {};
  int p = p0;
  for (; p + 4 <= p1; p += 4) {
    int s0 = csrsrc[p], s1 = csrsrc[p + 1], s2 = csrsrc[p + 2], s3 = csrsrc[p + 3];
    float e0 = als[s0] + ad; e0 = (e0 > 0.f) ? e0 : NSLOPE * e0;
    float e1 = als[s1] + ad; e1 = (e1 > 0.f) ? e1 : NSLOPE * e1;
    float e2 = als[s2] + ad; e2 = (e2 > 0.f) ? e2 : NSLOPE * e2;
    float e3 = als[s3] + ad; e3 = (e3 > 0.f) ? e3 : NSLOPE * e3;
    uint4 v0 = *(const uint4*)(h + (size_t)s0 * DD + l * 8);
    uint4 v1 = *(const uint4*)(h + (size_t)s1 * DD + l * 8);
    uint4 v2 = *(const uint4*)(h + (size_t)s2 * DD + l * 8);
    uint4 v3 = *(const uint4*)(h + (size_t)s3 * DD + l * 8);
    wacc8(a, v0, __expf(e0 - m) * invz);
    wacc8(a, v1, __expf(e1 - m) * invz);
    wacc8(a, v2, __expf(e2 - m) * invz);
    wacc8(a, v3, __expf(e3 - m) * invz);
  }
  for (; p < p1; ++p) {
    int s = csrsrc[p];
    float e = als[s] + ad; e = (e > 0.f) ? e : NSLOPE * e;
    uint4 v = *(const uint4*)(h + (size_t)s * DD + l * 8);
    wacc8(a, v, __expf(e - m) * invz);
  }
  float4 b0 = ((const float4*)bias)[l * 2];
  float4 b1 = ((const float4*)bias)[l * 2 + 1];
  float r0 = fmaxf(a[0] + b0.x, 0.f), r1 = fmaxf(a[1] + b0.y, 0.f);
  float r2 = fmaxf(a[2] + b0.z, 0.f), r3 = fmaxf(a[3] + b0.w, 0.f);
  float r4 = fmaxf(a[4] + b1.x, 0.f), r5 = fmaxf(a[5] + b1.y, 0.f);
  float r6 = fmaxf(a[6] + b1.z, 0.f), r7 = fmaxf(a[7] + b1.w, 0.f);
  uint4 o;
  o.x = (uint)f2bf(r0) | ((uint)f2bf(r1) << 16);
  o.y = (uint)f2bf(r2) | ((uint)f2bf(r3) << 16);
  o.z = (uint)f2bf(r4) | ((uint)f2bf(r5) << 16);
  o.w = (uint)f2bf(r6) | ((uint)f2bf(r7) << 16);
  *(uint4*)(out + (size_t)w * DD + l * 8) = o;
}

// ---------------- final GCN (H->40, rows pre-scaled by dinv) + log_softmax, fp32 out ----------------
__global__ __launch_bounds__(256) void k_gcn2_lsm(const u16* __restrict__ hs, const int* __restrict__ rowptr,
                                                  const int* __restrict__ csrsrc, const float* __restrict__ dinv,
                                                  const float* __restrict__ bias, float* __restrict__ out, int n) {
  int w = (blockIdx.x * blockDim.x + threadIdx.x) >> 6;
  int lane = threadIdx.x & 63;
  if (w >= n) return;
  int p0 = rowptr[w], p1 = rowptr[w + 1];
  float acc = 0.f;
  int p = p0;
  for (; p + 4 <= p1; p += 4) {
    int s0 = csrsrc[p], s1 = csrsrc[p + 1], s2 = csrsrc[p + 2], s3 = csrsrc[p + 3];
    if (lane < LL) {
      float v0 = bf2f(hs[(size_t)s0 * LL + lane]);
      float v1 = bf2f(hs[(size_t)s1 * LL + lane]);
      float v2 = bf2f(hs[(size_t)s2 * LL + lane]);
      float v3 = bf2f(hs[(size_t)s3 * LL + lane]);
      acc += v0 + v1 + v2 + v3;
    }
  }
  for (; p < p1; ++p) {
    int s = csrsrc[p];
    if (lane < LL) acc += bf2f(hs[(size_t)s * LL + lane]);
  }
  float dd = dinv[w];
  float v = (lane < LL) ? dd * acc + bias[lane] : -INFINITY;
  float m = v;
  #pragma unroll
  for (int off = 1; off < 64; off <<= 1) m = fmaxf(m, __shfl_xor(m, off));
  float ex = (lane < LL) ? __expf(v - m) : 0.f;
  float z = ex;
  #pragma unroll
  for (int off = 1; off < 64; off <<= 1) z += __shfl_xor(z, off);
  if (lane < LL) out[(size_t)w * LL + lane] = v - m - logf(z);
}

// ---------------- launch ----------------
extern "C" void kernel_launch(void* const* d_in, const int* in_sizes, int n_in,
                              void* d_out, int out_size, void* d_ws, size_t ws_size,
                              hipStream_t stream) {
  const float* x   = (const float*)d_in[0];
  const int*   ei  = (const int*)d_in[1];
  const float* W1  = (const float*)d_in[2];
  const float* b1  = (const float*)d_in[3];
  const float* Wg  = (const float*)d_in[4];
  const float* a_s = (const float*)d_in[5];
  const float* a_d = (const float*)d_in[6];
  const float* bg  = (const float*)d_in[7];
  const float* W2  = (const float*)d_in[8];
  const float* b2  = (const float*)d_in[9];
  float* out = (float*)d_out;

  const int n = in_sizes[0] / DD;
  const int E = in_sizes[1] / 2;
  const int M = E + n;
  const int* esrc = ei;
  const int* edst = ei + E;

  char* wp = (char*)d_ws;
  auto carve = [&](size_t bytes) -> char* {
    char* p = wp;
    wp += (bytes + 255) & ~(size_t)255;
    return p;
  };
  u16*   buf0   = (u16*)carve((size_t)n * DD * 2);
  u16*   buf1   = (u16*)carve((size_t)n * DD * 2);
  u16*   h40    = (u16*)carve((size_t)n * LL * 2);
  u16*   W1t    = (u16*)carve((size_t)DD * DD * 2);
  u16*   Wgt    = (u16*)carve((size_t)DD * DD * 2);
  u16*   W2t    = (u16*)carve((size_t)LL * DD * 2);
  int*   csrsrc = (int*)carve((size_t)M * 4);
  int*   rowptr = (int*)carve((size_t)(n + 1) * 4);
  int*   cursor = (int*)carve((size_t)n * 4);
  int*   degi   = (int*)carve((size_t)n * 4);
  int*   bsum   = (int*)carve(64 * 4);
  float* dinv   = (float*)carve((size_t)n * 4);
  float* alsA   = (float*)carve((size_t)n * 4);
  float* aldA   = (float*)carve((size_t)n * 4);
  float* alsB   = (float*)carve((size_t)n * 4);
  float* aldB   = (float*)carve((size_t)n * 4);
  float* csum   = (float*)carve(DD * 4);
  float* csq    = (float*)carve(DD * 4);
  float* mean   = (float*)carve(DD * 4);
  float* rstd   = (float*)carve(DD * 4);

  hipMemsetAsync(degi, 0, (size_t)n * 4, stream);
  hipMemsetAsync(csum, 0, DD * 4, stream);
  hipMemsetAsync(csq, 0, DD * 4, stream);
  hipMemsetAsync(alsA, 0, (size_t)n * 4, stream);
  hipMemsetAsync(aldA, 0, (size_t)n * 4, stream);
  hipMemsetAsync(alsB, 0, (size_t)n * 4, stream);
  hipMemsetAsync(aldB, 0, (size_t)n * 4, stream);

  // fused preprocessing
  const int rowsPerBlk = 32;
  int nbC = (n + rowsPerBlk - 1) / rowsPerBlk;   // colstats blocks
  int nbE = (E + 255) / 256;                     // count_deg blocks
  int nb  = (n + SCHUNK - 1) / SCHUNK;           // scan chunks
  int total4 = n * (DD / 4);
  int nbS = (total4 + 255) / 256;                // standardize blocks
  k_pre1<<<nbC + nbE + 3 * DD, 256, 0, stream>>>(x, csum, csq, n, rowsPerBlk, nbC,
                                                 edst, E, degi, nbE, W1, W1t, Wg, Wgt, W2, W2t);
  k_pre2<<<nb + 1, 256, 0, stream>>>(csum, csq, mean, rstd, n, degi, bsum, nb);
  k_scan_bsums<<<1, 64, 0, stream>>>(bsum, nb);
  k_pre4<<<nbS + nb, 256, 0, stream>>>(x, mean, rstd, buf0, total4, nbS,
                                       degi, bsum, rowptr, cursor, csrsrc, dinv, n);
  k_scatter<<<(E + 255) / 256, 256, 0, stream>>>(esrc, edst, E, cursor, csrsrc);

  dim3 blk(256);
  dim3 gemmGrid(DD / 128, (n + 127) / 128);   // 128x128 tiles for square GEMMs
  int aggGrid1 = (n + 3) / 4;   // 1 wave per node (k_gcn2_lsm)
  int aggGrid2 = (n + 7) / 8;   // 2 nodes per wave

  // layer 1: GCN(256->256) + relu  (GEMM epilogue pre-scales rows by dinv)
  k_mfma_gemm128<<<gemmGrid, blk, 0, stream>>>(buf0, W1t, buf1, n, DD, DD, dinv,
                                               nullptr, nullptr, nullptr, nullptr);
  k_gcn_agg<<<aggGrid2, blk, 0, stream>>>(buf1, rowptr, csrsrc, dinv, b1, buf0, n);

  // layer 2: GAT — GEMM emits h2 and fused logits (alsA/aldA)
  k_mfma_gemm128<<<gemmGrid, blk, 0, stream>>>(buf0, Wgt, buf1, n, DD, DD, nullptr,
                                               a_s, a_d, alsA, aldA);
  k_gat_agg<<<aggGrid2, blk, 0, stream>>>(buf1, rowptr, csrsrc, alsA, aldA, bg, buf0, n);

  // layer 3: GAT — GEMM emits h3 and fused logits (alsB/aldB)
  k_mfma_gemm128<<<gemmGrid, blk, 0, stream>>>(buf0, Wgt, buf1, n, DD, DD, nullptr,
                                               a_s, a_d, alsB, aldB);
  k_gat_agg<<<aggGrid2, blk, 0, stream>>>(buf1, rowptr, csrsrc, alsB, aldB, bg, buf0, n);

  // final: GCN(256->40) + log_softmax (rows pre-scaled by dinv)
  dim3 gemmGrid2(1, (n + 127) / 128);
  k_mfma_gemm<<<gemmGrid2, blk, 0, stream>>>(buf0, W2t, h40, n, LL, DD, dinv);
  k_gcn2_lsm<<<aggGrid1, blk, 0, stream>>>(h40, rowptr, csrsrc, dinv, b2, out, n);
}

// Round 11
// 553.430 us; speedup vs baseline: 1.1035x; 1.0058x over previous
//
#include <hip/hip_runtime.h>
#include <math.h>

#define DD 256      // input/hidden feature dim
#define LL 40       // output classes
#define NSLOPE 0.2f // PyG GATConv leaky_relu slope
#define SCHUNK 1024 // elements per scan block (n<=64*SCHUNK)
#define NPRIV 8     // privatized degree histogram copies

typedef unsigned short u16;
typedef unsigned int uint;
typedef __attribute__((ext_vector_type(8))) short short8;
typedef __attribute__((ext_vector_type(4))) float f32x4;

__device__ __forceinline__ float bf2f(u16 v) { return __uint_as_float(((uint)v) << 16); }
__device__ __forceinline__ u16 f2bf(float f) {
  uint u = __float_as_uint(f);
  return (u16)((u + 0x7fff + ((u >> 16) & 1)) >> 16);  // RNE
}
__device__ __forceinline__ void acc8(float* a, uint4 v) {
  a[0] += __uint_as_float(v.x << 16);
  a[1] += __uint_as_float(v.x & 0xffff0000u);
  a[2] += __uint_as_float(v.y << 16);
  a[3] += __uint_as_float(v.y & 0xffff0000u);
  a[4] += __uint_as_float(v.z << 16);
  a[5] += __uint_as_float(v.z & 0xffff0000u);
  a[6] += __uint_as_float(v.w << 16);
  a[7] += __uint_as_float(v.w & 0xffff0000u);
}
__device__ __forceinline__ void wacc8(float* a, uint4 v, float w) {
  a[0] += w * __uint_as_float(v.x << 16);
  a[1] += w * __uint_as_float(v.x & 0xffff0000u);
  a[2] += w * __uint_as_float(v.y << 16);
  a[3] += w * __uint_as_float(v.y & 0xffff0000u);
  a[4] += w * __uint_as_float(v.z << 16);
  a[5] += w * __uint_as_float(v.z & 0xffff0000u);
  a[6] += w * __uint_as_float(v.w << 16);
  a[7] += w * __uint_as_float(v.w & 0xffff0000u);
}

// ===== stage 1: colstats->partials (no atomics) | count_deg->8-way priv | convWt x3 =====
__global__ __launch_bounds__(256) void k_pre1(const float* __restrict__ x, float* __restrict__ partS,
                                              float* __restrict__ partQ, int n, int rowsPerBlk, int nbC,
                                              const int* __restrict__ edst, int E, int* __restrict__ degi8, int nbE,
                                              const float* __restrict__ W1, u16* __restrict__ W1t,
                                              const float* __restrict__ Wg, u16* __restrict__ Wgt,
                                              const float* __restrict__ W2, u16* __restrict__ W2t) {
  int b = blockIdx.x;
  int tid = threadIdx.x;
  if (b < nbC) {
    // colstats: thread = column, 8 explicit independent loads (R9-proven); plain partial store
    int r0 = b * rowsPerBlk;
    int r1 = min(r0 + rowsPerBlk, n);
    float s0 = 0.f, s1 = 0.f, s2 = 0.f, s3 = 0.f;
    float q0 = 0.f, q1 = 0.f, q2 = 0.f, q3 = 0.f;
    const float* xc = x + tid;
    int r = r0;
    for (; r + 8 <= r1; r += 8) {
      float v0 = xc[(size_t)(r + 0) * DD];
      float v1 = xc[(size_t)(r + 1) * DD];
      float v2 = xc[(size_t)(r + 2) * DD];
      float v3 = xc[(size_t)(r + 3) * DD];
      float v4 = xc[(size_t)(r + 4) * DD];
      float v5 = xc[(size_t)(r + 5) * DD];
      float v6 = xc[(size_t)(r + 6) * DD];
      float v7 = xc[(size_t)(r + 7) * DD];
      s0 += v0; q0 = fmaf(v0, v0, q0);
      s1 += v1; q1 = fmaf(v1, v1, q1);
      s2 += v2; q2 = fmaf(v2, v2, q2);
      s3 += v3; q3 = fmaf(v3, v3, q3);
      s0 += v4; q0 = fmaf(v4, v4, q0);
      s1 += v5; q1 = fmaf(v5, v5, q1);
      s2 += v6; q2 = fmaf(v6, v6, q2);
      s3 += v7; q3 = fmaf(v7, v7, q3);
    }
    for (; r < r1; ++r) {
      float v = xc[(size_t)r * DD];
      s0 += v; q0 = fmaf(v, v, q0);
    }
    partS[(size_t)b * DD + tid] = (s0 + s1) + (s2 + s3);
    partQ[(size_t)b * DD + tid] = (q0 + q1) + (q2 + q3);
  } else if (b < nbC + nbE) {
    int eb = b - nbC;
    int i = eb * 256 + tid;
    if (i < E) atomicAdd(&degi8[(size_t)(eb & (NPRIV - 1)) * n + edst[i]], 1);
  } else {
    int b2 = b - nbC - nbE;  // [0, 3*DD): weight convert+transpose
    if (b2 < DD) {
      int k = b2;
      for (int nn = tid; nn < DD; nn += 256) W1t[(size_t)nn * DD + k] = f2bf(W1[(size_t)k * DD + nn]);
    } else if (b2 < 2 * DD) {
      int k = b2 - DD;
      for (int nn = tid; nn < DD; nn += 256) Wgt[(size_t)nn * DD + k] = f2bf(Wg[(size_t)k * DD + nn]);
    } else {
      int k = b2 - 2 * DD;
      for (int nn = tid; nn < LL; nn += 256) W2t[(size_t)nn * DD + k] = f2bf(W2[(size_t)k * LL + nn]);
    }
  }
}

// ===== stage 2: blocksum (sums 8 priv copies) | partial-reduce -> csum/csq (16 atomics/address) =====
__global__ __launch_bounds__(256) void k_pre2(const int* __restrict__ degi8, int* __restrict__ bsum, int nb, int n,
                                              const float* __restrict__ partS, const float* __restrict__ partQ,
                                              float* __restrict__ csum, float* __restrict__ csq, int nbC) {
  int b = blockIdx.x;
  int tid = threadIdx.x;
  if (b < nb) {
    int base = b * SCHUNK;
    int end = min(base + SCHUNK, n);
    int s = 0;
    for (int i = base + tid; i < end; i += 256) {
      int dv = 1;  // self-loop
      #pragma unroll
      for (int k = 0; k < NPRIV; ++k) dv += degi8[(size_t)k * n + i];
      s += dv;
    }
    __shared__ int ws[4];
    #pragma unroll
    for (int off = 32; off >= 1; off >>= 1) s += __shfl_down(s, off);
    if ((tid & 63) == 0) ws[tid >> 6] = s;
    __syncthreads();
    if (tid == 0) bsum[b] = ws[0] + ws[1] + ws[2] + ws[3];
  } else {
    int pb = b - nb;             // 0..15
    int per = (nbC + 15) / 16;
    int b0 = pb * per, b1 = min(b0 + per, nbC);
    float s = 0.f, q = 0.f;
    for (int bb = b0; bb < b1; ++bb) {
      s += partS[(size_t)bb * DD + tid];
      q += partQ[(size_t)bb * DD + tid];
    }
    atomicAdd(&csum[tid], s);
    atomicAdd(&csq[tid], q);
  }
}

// ===== stage 3: scan of block sums | finalize stats =====
__global__ __launch_bounds__(256) void k_pre3(int* __restrict__ bsum, int nb,
                                              const float* __restrict__ csum, const float* __restrict__ csq,
                                              float* __restrict__ mean, float* __restrict__ rstd, int n) {
  int tid = threadIdx.x;
  if (blockIdx.x == 0) {
    if (tid < 64) {
      int orig = (tid < nb) ? bsum[tid] : 0;
      int v = orig;
      #pragma unroll
      for (int off = 1; off < 64; off <<= 1) {
        int t = __shfl_up(v, off);
        if (tid >= off) v += t;
      }
      if (tid < nb) bsum[tid] = v - orig;  // exclusive
    }
  } else {
    float s = csum[tid], q = csq[tid];
    float m = s / (float)n;
    float var = (q - s * m) / (float)(n - 1);   // unbiased, ddof=1
    mean[tid] = m;
    rstd[tid] = 1.0f / sqrtf(var);
  }
}

// ===== stage 4: standardize | rowptr_write (+selfloop slot 0; deg from 8 priv copies) =====
__global__ __launch_bounds__(256) void k_pre4(const float* __restrict__ x, const float* __restrict__ mean,
                                              const float* __restrict__ rstd, u16* __restrict__ xs,
                                              int total4, int nbS,
                                              const int* __restrict__ degi8, const int* __restrict__ bsum,
                                              int* __restrict__ rowptr, int* __restrict__ cursor,
                                              int* __restrict__ csrsrc, float* __restrict__ dinv, int n) {
  int b = blockIdx.x;
  int tid = threadIdx.x;
  if (b < nbS) {
    int i = b * 256 + tid;
    if (i >= total4) return;
    int c4 = i & (DD / 4 - 1);
    float4 v = ((const float4*)x)[i];
    float4 m = ((const float4*)mean)[c4];
    float4 r = ((const float4*)rstd)[c4];
    uint2 o;
    o.x = (uint)f2bf((v.x - m.x) * r.x) | ((uint)f2bf((v.y - m.y) * r.y) << 16);
    o.y = (uint)f2bf((v.z - m.z) * r.z) | ((uint)f2bf((v.w - m.w) * r.w) << 16);
    ((uint2*)xs)[i] = o;
  } else {
    int bb = b - nbS;
    int base = bb * SCHUNK + tid * 4;
    int d[4];
    int t = 0;
    #pragma unroll
    for (int j = 0; j < 4; ++j) {
      int i = base + j;
      int dv = 0;
      if (i < n) {
        dv = 1;
        #pragma unroll
        for (int k = 0; k < NPRIV; ++k) dv += degi8[(size_t)k * n + i];
      }
      d[j] = dv;
      t += dv;
    }
    __shared__ int sc[256];
    sc[tid] = t;
    __syncthreads();
    for (int off = 1; off < 256; off <<= 1) {
      int v = 0;
      if (tid >= off) v = sc[tid - off];
      __syncthreads();
      if (tid >= off) sc[tid] += v;
      __syncthreads();
    }
    int run = bsum[bb] + sc[tid] - t;
    #pragma unroll
    for (int j = 0; j < 4; ++j) {
      int i = base + j;
      if (i < n) {
        rowptr[i] = run;
        csrsrc[run] = i;       // self-loop occupies slot 0 of each row
        cursor[i] = run + 1;   // edges fill after it
        dinv[i] = rsqrtf((float)d[j]);
        run += d[j];
        if (i == n - 1) rowptr[n] = run;
      }
    }
  }
}

__global__ void k_scatter(const int* __restrict__ esrc, const int* __restrict__ edst, int E,
                          int* __restrict__ cursor, int* __restrict__ csrsrc) {
  int i = blockIdx.x * blockDim.x + threadIdx.x;
  if (i < E) {
    int d = edst[i];
    int p = atomicAdd(&cursor[d], 1);
    csrsrc[p] = esrc[i];
  }
}

// ---------------- bf16 MFMA GEMM, 128x128 tile; optional row scale; optional fused attention logits ----------------
__global__ __launch_bounds__(256) void k_mfma_gemm128(const u16* __restrict__ A, const u16* __restrict__ Bt,
                                                      u16* __restrict__ C, int M, int N, int K,
                                                      const float* __restrict__ rowScale,
                                                      const float* __restrict__ aS, const float* __restrict__ aD,
                                                      float* __restrict__ als, float* __restrict__ ald) {
  __shared__ u16 As[128 * 40];  // [128][32+8] pad -> 2-way (free) LDS banking
  __shared__ u16 Bs[128 * 40];
  int tid = threadIdx.x;
  int wave = tid >> 6, lane = tid & 63, quad = lane >> 4, l16 = lane & 15;
  int rowBase = blockIdx.y * 128, colBase = blockIdx.x * 128;
  f32x4 acc[2][8] = {};
  for (int k0 = 0; k0 < K; k0 += 32) {
    #pragma unroll
    for (int i = 0; i < 2; ++i) {
      int ch = tid + i * 256;
      int r = ch >> 2, cc = (ch & 3) * 8;
      int gr = min(rowBase + r, M - 1);  // clamp: junk rows never stored
      *(uint4*)&As[r * 40 + cc] = *(const uint4*)(A + (size_t)gr * K + k0 + cc);
      *(uint4*)&Bs[r * 40 + cc] = *(const uint4*)(Bt + (size_t)(colBase + r) * K + k0 + cc);
    }
    __syncthreads();
    short8 af0 = *(const short8*)&As[(wave * 32 + l16) * 40 + quad * 8];
    short8 af1 = *(const short8*)&As[(wave * 32 + 16 + l16) * 40 + quad * 8];
    #pragma unroll
    for (int j = 0; j < 8; ++j) {
      short8 bf = *(const short8*)&Bs[(j * 16 + l16) * 40 + quad * 8];
      acc[0][j] = __builtin_amdgcn_mfma_f32_16x16x32_bf16(af0, bf, acc[0][j], 0, 0, 0);
      acc[1][j] = __builtin_amdgcn_mfma_f32_16x16x32_bf16(af1, bf, acc[1][j], 0, 0, 0);
    }
    __syncthreads();
  }
  // C/D layout: col=lane&15, row=quad*4+reg
  #pragma unroll
  for (int i = 0; i < 2; ++i) {
    #pragma unroll
    for (int r = 0; r < 4; ++r) {
      int gr = rowBase + wave * 32 + i * 16 + quad * 4 + r;
      if (gr >= M) continue;
      float sc = rowScale ? rowScale[gr] : 1.0f;
      #pragma unroll
      for (int j = 0; j < 8; ++j) {
        int gc = colBase + j * 16 + l16;
        C[(size_t)gr * N + gc] = f2bf(acc[i][j][r] * sc);
      }
      if (aS) {  // fused partial attention logits for this 128-col slice
        float t1 = 0.f, t2 = 0.f;
        #pragma unroll
        for (int j = 0; j < 8; ++j) {
          int gc = colBase + j * 16 + l16;
          float v = acc[i][j][r];
          t1 = fmaf(v, aS[gc], t1);
          t2 = fmaf(v, aD[gc], t2);
        }
        #pragma unroll
        for (int off = 1; off < 16; off <<= 1) {
          t1 += __shfl_xor(t1, off);
          t2 += __shfl_xor(t2, off);
        }
        if (l16 == 0) {
          atomicAdd(&als[gr], t1);
          atomicAdd(&ald[gr], t2);
        }
      }
    }
  }
}

// ---------------- bf16 MFMA GEMM, 128x64 tile (generic N, used for final W2) ----------------
__global__ __launch_bounds__(256) void k_mfma_gemm(const u16* __restrict__ A, const u16* __restrict__ Bt,
                                                   u16* __restrict__ C, int M, int N, int K,
                                                   const float* __restrict__ rowScale) {
  __shared__ u16 As[128 * 40];
  __shared__ u16 Bs[64 * 40];
  int tid = threadIdx.x;
  int wave = tid >> 6, lane = tid & 63, quad = lane >> 4, l16 = lane & 15;
  int rowBase = blockIdx.y * 128, colBase = blockIdx.x * 64;
  f32x4 acc[2][4] = {};
  for (int k0 = 0; k0 < K; k0 += 32) {
    #pragma unroll
    for (int i = 0; i < 2; ++i) {
      int ch = tid + i * 256;
      int r = ch >> 2, cc = (ch & 3) * 8;
      int gr = rowBase + r;
      uint4 v = make_uint4(0, 0, 0, 0);
      if (gr < M) v = *(const uint4*)(A + (size_t)gr * K + k0 + cc);
      *(uint4*)&As[r * 40 + cc] = v;
    }
    {
      int r = tid >> 2, cc = (tid & 3) * 8;
      int gn = colBase + r;
      uint4 v = make_uint4(0, 0, 0, 0);
      if (gn < N) v = *(const uint4*)(Bt + (size_t)gn * K + k0 + cc);
      *(uint4*)&Bs[r * 40 + cc] = v;
    }
    __syncthreads();
    short8 af[2];
    af[0] = *(const short8*)&As[(wave * 32 + l16) * 40 + quad * 8];
    af[1] = *(const short8*)&As[(wave * 32 + 16 + l16) * 40 + quad * 8];
    short8 bf[4];
    #pragma unroll
    for (int j = 0; j < 4; ++j) bf[j] = *(const short8*)&Bs[(j * 16 + l16) * 40 + quad * 8];
    #pragma unroll
    for (int i = 0; i < 2; ++i)
      #pragma unroll
      for (int j = 0; j < 4; ++j)
        acc[i][j] = __builtin_amdgcn_mfma_f32_16x16x32_bf16(af[i], bf[j], acc[i][j], 0, 0, 0);
    __syncthreads();
  }
  #pragma unroll
  for (int i = 0; i < 2; ++i) {
    #pragma unroll
    for (int r = 0; r < 4; ++r) {
      int gr = rowBase + wave * 32 + i * 16 + quad * 4 + r;
      if (gr >= M) continue;
      float sc = rowScale ? rowScale[gr] : 1.0f;
      #pragma unroll
      for (int j = 0; j < 4; ++j) {
        int gc = colBase + j * 16 + l16;
        if (gc < N) C[(size_t)gr * N + gc] = f2bf(acc[i][j][r] * sc);
      }
    }
  }
}

// ---------------- GCN aggregate (rows pre-scaled by dinv[s]): out[d]=relu(dinv[d]*sum + b) ----------------
__global__ __launch_bounds__(256) void k_gcn_agg(const u16* __restrict__ hs, const int* __restrict__ rowptr,
                                                 const int* __restrict__ csrsrc, const float* __restrict__ dinv,
                                                 const float* __restrict__ bias, u16* __restrict__ out, int n) {
  int wave = (blockIdx.x * blockDim.x + threadIdx.x) >> 6;
  int lane = threadIdx.x & 63;
  int sub = lane >> 5, l = lane & 31;
  int w = wave * 2 + sub;
  if (w >= n) return;
  int p0 = rowptr[w], p1 = rowptr[w + 1];
  float a[8] = {};
  int p = p0;
  for (; p + 4 <= p1; p += 4) {
    int s0 = csrsrc[p], s1 = csrsrc[p + 1], s2 = csrsrc[p + 2], s3 = csrsrc[p + 3];
    uint4 v0 = *(const uint4*)(hs + (size_t)s0 * DD + l * 8);
    uint4 v1 = *(const uint4*)(hs + (size_t)s1 * DD + l * 8);
    uint4 v2 = *(const uint4*)(hs + (size_t)s2 * DD + l * 8);
    uint4 v3 = *(const uint4*)(hs + (size_t)s3 * DD + l * 8);
    acc8(a, v0); acc8(a, v1); acc8(a, v2); acc8(a, v3);
  }
  for (; p < p1; ++p) {
    int s = csrsrc[p];
    uint4 v = *(const uint4*)(hs + (size_t)s * DD + l * 8);
    acc8(a, v);
  }
  float dd = dinv[w];
  float4 b0 = ((const float4*)bias)[l * 2];
  float4 b1 = ((const float4*)bias)[l * 2 + 1];
  float r0 = fmaxf(dd * a[0] + b0.x, 0.f), r1 = fmaxf(dd * a[1] + b0.y, 0.f);
  float r2 = fmaxf(dd * a[2] + b0.z, 0.f), r3 = fmaxf(dd * a[3] + b0.w, 0.f);
  float r4 = fmaxf(dd * a[4] + b1.x, 0.f), r5 = fmaxf(dd * a[5] + b1.y, 0.f);
  float r6 = fmaxf(dd * a[6] + b1.z, 0.f), r7 = fmaxf(dd * a[7] + b1.w, 0.f);
  uint4 o;
  o.x = (uint)f2bf(r0) | ((uint)f2bf(r1) << 16);
  o.y = (uint)f2bf(r2) | ((uint)f2bf(r3) << 16);
  o.z = (uint)f2bf(r4) | ((uint)f2bf(r5) << 16);
  o.w = (uint)f2bf(r6) | ((uint)f2bf(r7) << 16);
  *(uint4*)(out + (size_t)w * DD + l * 8) = o;
}

// ---------------- GAT aggregate: online segment softmax + weighted sum + bias + relu ----------------
__global__ __launch_bounds__(256) void k_gat_agg(const u16* __restrict__ h, const int* __restrict__ rowptr,
                                                 const int* __restrict__ csrsrc, const float* __restrict__ als,
                                                 const float* __restrict__ ald, const float* __restrict__ bias,
                                                 u16* __restrict__ out, int n) {
  int wave = (blockIdx.x * blockDim.x + threadIdx.x) >> 6;
  int lane = threadIdx.x & 63;
  int sub = lane >> 5, l = lane & 31;
  int w = wave * 2 + sub;
  if (w >= n) return;
  float ad = ald[w];
  int p0 = rowptr[w], p1 = rowptr[w + 1];
  // pass 1: online softmax stats, lanes stride edges within half-wave
  float m = -1e30f, z = 0.f;
  for (int p = p0 + l; p < p1; p += 32) {
    float e = als[csrsrc[p]] + ad;
    e = (e > 0.f) ? e : NSLOPE * e;
    if (e > m) { z = z * __expf(m - e) + 1.f; m = e; }
    else z += __expf(e - m);
  }
  #pragma unroll
  for (int off = 16; off >= 1; off >>= 1) {
    float m2 = __shfl_xor(m, off), z2 = __shfl_xor(z, off);
    float M = fmaxf(m, m2);
    z = z * __expf(m - M) + z2 * __expf(m2 - M);
    m = M;
  }
  float invz = 1.0f / z;
  // pass 2: weighted feature accumulation, lane owns 8 features, unroll x4
  float a[8] = {};
  int p = p0;
  for (; p + 4 <= p1; p += 4) {
    int s0 = csrsrc[p], s1 = csrsrc[p + 1], s2 = csrsrc[p + 2], s3 = csrsrc[p + 3];
    float e0 = als[s0] + ad; e0 = (e0 > 0.f) ? e0 : NSLOPE * e0;
    float e1 = als[s1] + ad; e1 = (e1 > 0.f) ? e1 : NSLOPE * e1;
    float e2 = als[s2] + ad; e2 = (e2 > 0.f) ? e2 : NSLOPE * e2;
    float e3 = als[s3] + ad; e3 = (e3 > 0.f) ? e3 : NSLOPE * e3;
    uint4 v0 = *(const uint4*)(h + (size_t)s0 * DD + l * 8);
    uint4 v1 = *(const uint4*)(h + (size_t)s1 * DD + l * 8);
    uint4 v2 = *(const uint4*)(h + (size_t)s2 * DD + l * 8);
    uint4 v3 = *(const uint4*)(h + (size_t)s3 * DD + l * 8);
    wacc8(a, v0, __expf(e0 - m) * invz);
    wacc8(a, v1, __expf(e1 - m) * invz);
    wacc8(a, v2, __expf(e2 - m) * invz);
    wacc8(a, v3, __expf(e3 - m) * invz);
  }
  for (; p < p1; ++p) {
    int s = csrsrc[p];
    float e = als[s] + ad; e = (e > 0.f) ? e : NSLOPE * e;
    uint4 v = *(const uint4*)(h + (size_t)s * DD + l * 8);
    wacc8(a, v, __expf(e - m) * invz);
  }
  float4 b0 = ((const float4*)bias)[l * 2];
  float4 b1 = ((const float4*)bias)[l * 2 + 1];
  float r0 = fmaxf(a[0] + b0.x, 0.f), r1 = fmaxf(a[1] + b0.y, 0.f);
  float r2 = fmaxf(a[2] + b0.z, 0.f), r3 = fmaxf(a[3] + b0.w, 0.f);
  float r4 = fmaxf(a[4] + b1.x, 0.f), r5 = fmaxf(a[5] + b1.y, 0.f);
  float r6 = fmaxf(a[6] + b1.z, 0.f), r7 = fmaxf(a[7] + b1.w, 0.f);
  uint4 o;
  o.x = (uint)f2bf(r0) | ((uint)f2bf(r1) << 16);
  o.y = (uint)f2bf(r2) | ((uint)f2bf(r3) << 16);
  o.z = (uint)f2bf(r4) | ((uint)f2bf(r5) << 16);
  o.w = (uint)f2bf(r6) | ((uint)f2bf(r7) << 16);
  *(uint4*)(out + (size_t)w * DD + l * 8) = o;
}

// ---------------- final GCN (H->40, rows pre-scaled by dinv) + log_softmax, fp32 out ----------------
__global__ __launch_bounds__(256) void k_gcn2_lsm(const u16* __restrict__ hs, const int* __restrict__ rowptr,
                                                  const int* __restrict__ csrsrc, const float* __restrict__ dinv,
                                                  const float* __restrict__ bias, float* __restrict__ out, int n) {
  int w = (blockIdx.x * blockDim.x + threadIdx.x) >> 6;
  int lane = threadIdx.x & 63;
  if (w >= n) return;
  int p0 = rowptr[w], p1 = rowptr[w + 1];
  float acc = 0.f;
  int p = p0;
  for (; p + 4 <= p1; p += 4) {
    int s0 = csrsrc[p], s1 = csrsrc[p + 1], s2 = csrsrc[p + 2], s3 = csrsrc[p + 3];
    if (lane < LL) {
      float v0 = bf2f(hs[(size_t)s0 * LL + lane]);
      float v1 = bf2f(hs[(size_t)s1 * LL + lane]);
      float v2 = bf2f(hs[(size_t)s2 * LL + lane]);
      float v3 = bf2f(hs[(size_t)s3 * LL + lane]);
      acc += v0 + v1 + v2 + v3;
    }
  }
  for (; p < p1; ++p) {
    int s = csrsrc[p];
    if (lane < LL) acc += bf2f(hs[(size_t)s * LL + lane]);
  }
  float dd = dinv[w];
  float v = (lane < LL) ? dd * acc + bias[lane] : -INFINITY;
  float m = v;
  #pragma unroll
  for (int off = 1; off < 64; off <<= 1) m = fmaxf(m, __shfl_xor(m, off));
  float ex = (lane < LL) ? __expf(v - m) : 0.f;
  float z = ex;
  #pragma unroll
  for (int off = 1; off < 64; off <<= 1) z += __shfl_xor(z, off);
  if (lane < LL) out[(size_t)w * LL + lane] = v - m - logf(z);
}

// ---------------- launch ----------------
extern "C" void kernel_launch(void* const* d_in, const int* in_sizes, int n_in,
                              void* d_out, int out_size, void* d_ws, size_t ws_size,
                              hipStream_t stream) {
  const float* x   = (const float*)d_in[0];
  const int*   ei  = (const int*)d_in[1];
  const float* W1  = (const float*)d_in[2];
  const float* b1  = (const float*)d_in[3];
  const float* Wg  = (const float*)d_in[4];
  const float* a_s = (const float*)d_in[5];
  const float* a_d = (const float*)d_in[6];
  const float* bg  = (const float*)d_in[7];
  const float* W2  = (const float*)d_in[8];
  const float* b2  = (const float*)d_in[9];
  float* out = (float*)d_out;

  const int n = in_sizes[0] / DD;
  const int E = in_sizes[1] / 2;
  const int M = E + n;
  const int* esrc = ei;
  const int* edst = ei + E;

  char* wp = (char*)d_ws;
  auto carve = [&](size_t bytes) -> char* {
    char* p = wp;
    wp += (bytes + 255) & ~(size_t)255;
    return p;
  };
  const int rowsPerBlk = 32;
  int nbC = (n + rowsPerBlk - 1) / rowsPerBlk;   // colstats blocks
  int nbE = (E + 255) / 256;                     // count_deg blocks
  int nb  = (n + SCHUNK - 1) / SCHUNK;           // scan chunks
  int total4 = n * (DD / 4);
  int nbS = (total4 + 255) / 256;                // standardize blocks

  u16*   buf0   = (u16*)carve((size_t)n * DD * 2);
  u16*   buf1   = (u16*)carve((size_t)n * DD * 2);
  u16*   h40    = (u16*)carve((size_t)n * LL * 2);
  u16*   W1t    = (u16*)carve((size_t)DD * DD * 2);
  u16*   Wgt    = (u16*)carve((size_t)DD * DD * 2);
  u16*   W2t    = (u16*)carve((size_t)LL * DD * 2);
  int*   csrsrc = (int*)carve((size_t)M * 4);
  int*   rowptr = (int*)carve((size_t)(n + 1) * 4);
  int*   cursor = (int*)carve((size_t)n * 4);
  int*   degi8  = (int*)carve((size_t)NPRIV * n * 4);
  int*   bsum   = (int*)carve(64 * 4);
  float* dinv   = (float*)carve((size_t)n * 4);
  float* alsA   = (float*)carve((size_t)n * 4);
  float* aldA   = (float*)carve((size_t)n * 4);
  float* alsB   = (float*)carve((size_t)n * 4);
  float* aldB   = (float*)carve((size_t)n * 4);
  float* partS  = (float*)carve((size_t)nbC * DD * 4);
  float* partQ  = (float*)carve((size_t)nbC * DD * 4);
  float* csum   = (float*)carve(DD * 4);
  float* csq    = (float*)carve(DD * 4);
  float* mean   = (float*)carve(DD * 4);
  float* rstd   = (float*)carve(DD * 4);

  hipMemsetAsync(degi8, 0, (size_t)NPRIV * n * 4, stream);
  hipMemsetAsync(csum, 0, DD * 4, stream);
  hipMemsetAsync(csq, 0, DD * 4, stream);
  hipMemsetAsync(alsA, 0, (size_t)n * 4, stream);
  hipMemsetAsync(aldA, 0, (size_t)n * 4, stream);
  hipMemsetAsync(alsB, 0, (size_t)n * 4, stream);
  hipMemsetAsync(aldB, 0, (size_t)n * 4, stream);

  // fused preprocessing (atomic-light)
  k_pre1<<<nbC + nbE + 3 * DD, 256, 0, stream>>>(x, partS, partQ, n, rowsPerBlk, nbC,
                                                 edst, E, degi8, nbE, W1, W1t, Wg, Wgt, W2, W2t);
  k_pre2<<<nb + 16, 256, 0, stream>>>(degi8, bsum, nb, n, partS, partQ, csum, csq, nbC);
  k_pre3<<<2, 256, 0, stream>>>(bsum, nb, csum, csq, mean, rstd, n);
  k_pre4<<<nbS + nb, 256, 0, stream>>>(x, mean, rstd, buf0, total4, nbS,
                                       degi8, bsum, rowptr, cursor, csrsrc, dinv, n);
  k_scatter<<<(E + 255) / 256, 256, 0, stream>>>(esrc, edst, E, cursor, csrsrc);

  dim3 blk(256);
  dim3 gemmGrid(DD / 128, (n + 127) / 128);   // 128x128 tiles for square GEMMs
  int aggGrid1 = (n + 3) / 4;   // 1 wave per node (k_gcn2_lsm)
  int aggGrid2 = (n + 7) / 8;   // 2 nodes per wave

  // layer 1: GCN(256->256) + relu  (GEMM epilogue pre-scales rows by dinv)
  k_mfma_gemm128<<<gemmGrid, blk, 0, stream>>>(buf0, W1t, buf1, n, DD, DD, dinv,
                                               nullptr, nullptr, nullptr, nullptr);
  k_gcn_agg<<<aggGrid2, blk, 0, stream>>>(buf1, rowptr, csrsrc, dinv, b1, buf0, n);

  // layer 2: GAT — GEMM emits h2 and fused logits (alsA/aldA)
  k_mfma_gemm128<<<gemmGrid, blk, 0, stream>>>(buf0, Wgt, buf1, n, DD, DD, nullptr,
                                               a_s, a_d, alsA, aldA);
  k_gat_agg<<<aggGrid2, blk, 0, stream>>>(buf1, rowptr, csrsrc, alsA, aldA, bg, buf0, n);

  // layer 3: GAT — GEMM emits h3 and fused logits (alsB/aldB)
  k_mfma_gemm128<<<gemmGrid, blk, 0, stream>>>(buf0, Wgt, buf1, n, DD, DD, nullptr,
                                               a_s, a_d, alsB, aldB);
  k_gat_agg<<<aggGrid2, blk, 0, stream>>>(buf1, rowptr, csrsrc, alsB, aldB, bg, buf0, n);

  // final: GCN(256->40) + log_softmax (rows pre-scaled by dinv)
  dim3 gemmGrid2(1, (n + 127) / 128);
  k_mfma_gemm<<<gemmGrid2, blk, 0, stream>>>(buf0, W2t, h40, n, LL, DD, dinv);
  k_gcn2_lsm<<<aggGrid1, blk, 0, stream>>>(h40, rowptr, csrsrc, dinv, b2, out, n);
}

// Round 12
// 544.300 us; speedup vs baseline: 1.1220x; 1.0168x over previous
//
#include <hip/hip_runtime.h>
#include <math.h>

#define DD 256      // input/hidden feature dim
#define LL 40       // output classes
#define NSLOPE 0.2f // PyG GATConv leaky_relu slope
#define SCHUNK 1024 // elements per scan block (n<=64*SCHUNK)
#define NPRIV 8     // privatized degree histogram copies

typedef unsigned short u16;
typedef unsigned int uint;
typedef __attribute__((ext_vector_type(8))) short short8;
typedef __attribute__((ext_vector_type(4))) float f32x4;

__device__ __forceinline__ float bf2f(u16 v) { return __uint_as_float(((uint)v) << 16); }
__device__ __forceinline__ u16 f2bf(float f) {
  uint u = __float_as_uint(f);
  return (u16)((u + 0x7fff + ((u >> 16) & 1)) >> 16);  // RNE
}
__device__ __forceinline__ void acc8(float* a, uint4 v) {
  a[0] += __uint_as_float(v.x << 16);
  a[1] += __uint_as_float(v.x & 0xffff0000u);
  a[2] += __uint_as_float(v.y << 16);
  a[3] += __uint_as_float(v.y & 0xffff0000u);
  a[4] += __uint_as_float(v.z << 16);
  a[5] += __uint_as_float(v.z & 0xffff0000u);
  a[6] += __uint_as_float(v.w << 16);
  a[7] += __uint_as_float(v.w & 0xffff0000u);
}
__device__ __forceinline__ void wacc8(float* a, uint4 v, float w) {
  a[0] += w * __uint_as_float(v.x << 16);
  a[1] += w * __uint_as_float(v.x & 0xffff0000u);
  a[2] += w * __uint_as_float(v.y << 16);
  a[3] += w * __uint_as_float(v.y & 0xffff0000u);
  a[4] += w * __uint_as_float(v.z << 16);
  a[5] += w * __uint_as_float(v.z & 0xffff0000u);
  a[6] += w * __uint_as_float(v.w << 16);
  a[7] += w * __uint_as_float(v.w & 0xffff0000u);
}

// ===== stage 1: colstats->partials (no atomics) | count_deg->8-way priv | convWt x3 =====
__global__ __launch_bounds__(256) void k_pre1(const float* __restrict__ x, float* __restrict__ partS,
                                              float* __restrict__ partQ, int n, int rowsPerBlk, int nbC,
                                              const int* __restrict__ edst, int E, int* __restrict__ degi8, int nbE,
                                              const float* __restrict__ W1, u16* __restrict__ W1t,
                                              const float* __restrict__ Wg, u16* __restrict__ Wgt,
                                              const float* __restrict__ W2, u16* __restrict__ W2t) {
  int b = blockIdx.x;
  int tid = threadIdx.x;
  if (b < nbC) {
    // colstats: thread = column, 8 explicit independent loads (R9-proven); plain partial store
    int r0 = b * rowsPerBlk;
    int r1 = min(r0 + rowsPerBlk, n);
    float s0 = 0.f, s1 = 0.f, s2 = 0.f, s3 = 0.f;
    float q0 = 0.f, q1 = 0.f, q2 = 0.f, q3 = 0.f;
    const float* xc = x + tid;
    int r = r0;
    for (; r + 8 <= r1; r += 8) {
      float v0 = xc[(size_t)(r + 0) * DD];
      float v1 = xc[(size_t)(r + 1) * DD];
      float v2 = xc[(size_t)(r + 2) * DD];
      float v3 = xc[(size_t)(r + 3) * DD];
      float v4 = xc[(size_t)(r + 4) * DD];
      float v5 = xc[(size_t)(r + 5) * DD];
      float v6 = xc[(size_t)(r + 6) * DD];
      float v7 = xc[(size_t)(r + 7) * DD];
      s0 += v0; q0 = fmaf(v0, v0, q0);
      s1 += v1; q1 = fmaf(v1, v1, q1);
      s2 += v2; q2 = fmaf(v2, v2, q2);
      s3 += v3; q3 = fmaf(v3, v3, q3);
      s0 += v4; q0 = fmaf(v4, v4, q0);
      s1 += v5; q1 = fmaf(v5, v5, q1);
      s2 += v6; q2 = fmaf(v6, v6, q2);
      s3 += v7; q3 = fmaf(v7, v7, q3);
    }
    for (; r < r1; ++r) {
      float v = xc[(size_t)r * DD];
      s0 += v; q0 = fmaf(v, v, q0);
    }
    partS[(size_t)b * DD + tid] = (s0 + s1) + (s2 + s3);
    partQ[(size_t)b * DD + tid] = (q0 + q1) + (q2 + q3);
  } else if (b < nbC + nbE) {
    int eb = b - nbC;
    int i = eb * 256 + tid;
    if (i < E) atomicAdd(&degi8[(size_t)(eb & (NPRIV - 1)) * n + edst[i]], 1);
  } else {
    int b2 = b - nbC - nbE;  // [0, 3*DD): weight convert+transpose
    if (b2 < DD) {
      int k = b2;
      for (int nn = tid; nn < DD; nn += 256) W1t[(size_t)nn * DD + k] = f2bf(W1[(size_t)k * DD + nn]);
    } else if (b2 < 2 * DD) {
      int k = b2 - DD;
      for (int nn = tid; nn < DD; nn += 256) Wgt[(size_t)nn * DD + k] = f2bf(Wg[(size_t)k * DD + nn]);
    } else {
      int k = b2 - 2 * DD;
      for (int nn = tid; nn < LL; nn += 256) W2t[(size_t)nn * DD + k] = f2bf(W2[(size_t)k * LL + nn]);
    }
  }
}

// ===== stage 2: blocksum (sums 8 priv copies) | partial-reduce -> csum/csq =====
__global__ __launch_bounds__(256) void k_pre2(const int* __restrict__ degi8, int* __restrict__ bsum, int nb, int n,
                                              const float* __restrict__ partS, const float* __restrict__ partQ,
                                              float* __restrict__ csum, float* __restrict__ csq, int nbC) {
  int b = blockIdx.x;
  int tid = threadIdx.x;
  if (b < nb) {
    int base = b * SCHUNK;
    int end = min(base + SCHUNK, n);
    int s = 0;
    for (int i = base + tid; i < end; i += 256) {
      int dv = 1;  // self-loop
      #pragma unroll
      for (int k = 0; k < NPRIV; ++k) dv += degi8[(size_t)k * n + i];
      s += dv;
    }
    __shared__ int ws[4];
    #pragma unroll
    for (int off = 32; off >= 1; off >>= 1) s += __shfl_down(s, off);
    if ((tid & 63) == 0) ws[tid >> 6] = s;
    __syncthreads();
    if (tid == 0) bsum[b] = ws[0] + ws[1] + ws[2] + ws[3];
  } else {
    int pb = b - nb;             // 0..15
    int per = (nbC + 15) / 16;
    int b0 = pb * per, b1 = min(b0 + per, nbC);
    float s = 0.f, q = 0.f;
    for (int bb = b0; bb < b1; ++bb) {
      s += partS[(size_t)bb * DD + tid];
      q += partQ[(size_t)bb * DD + tid];
    }
    atomicAdd(&csum[tid], s);
    atomicAdd(&csq[tid], q);
  }
}

// ===== stage 3: scan of block sums | finalize stats =====
__global__ __launch_bounds__(256) void k_pre3(int* __restrict__ bsum, int nb,
                                              const float* __restrict__ csum, const float* __restrict__ csq,
                                              float* __restrict__ mean, float* __restrict__ rstd, int n) {
  int tid = threadIdx.x;
  if (blockIdx.x == 0) {
    if (tid < 64) {
      int orig = (tid < nb) ? bsum[tid] : 0;
      int v = orig;
      #pragma unroll
      for (int off = 1; off < 64; off <<= 1) {
        int t = __shfl_up(v, off);
        if (tid >= off) v += t;
      }
      if (tid < nb) bsum[tid] = v - orig;  // exclusive
    }
  } else {
    float s = csum[tid], q = csq[tid];
    float m = s / (float)n;
    float var = (q - s * m) / (float)(n - 1);   // unbiased, ddof=1
    mean[tid] = m;
    rstd[tid] = 1.0f / sqrtf(var);
  }
}

// ===== stage 4: standardize | rowptr_write (+selfloop slot 0; deg from 8 priv copies) =====
__global__ __launch_bounds__(256) void k_pre4(const float* __restrict__ x, const float* __restrict__ mean,
                                              const float* __restrict__ rstd, u16* __restrict__ xs,
                                              int total4, int nbS,
                                              const int* __restrict__ degi8, const int* __restrict__ bsum,
                                              int* __restrict__ rowptr, int* __restrict__ cursor,
                                              int* __restrict__ csrsrc, float* __restrict__ dinv, int n) {
  int b = blockIdx.x;
  int tid = threadIdx.x;
  if (b < nbS) {
    int i = b * 256 + tid;
    if (i >= total4) return;
    int c4 = i & (DD / 4 - 1);
    float4 v = ((const float4*)x)[i];
    float4 m = ((const float4*)mean)[c4];
    float4 r = ((const float4*)rstd)[c4];
    uint2 o;
    o.x = (uint)f2bf((v.x - m.x) * r.x) | ((uint)f2bf((v.y - m.y) * r.y) << 16);
    o.y = (uint)f2bf((v.z - m.z) * r.z) | ((uint)f2bf((v.w - m.w) * r.w) << 16);
    ((uint2*)xs)[i] = o;
  } else {
    int bb = b - nbS;
    int base = bb * SCHUNK + tid * 4;
    int d[4];
    int t = 0;
    #pragma unroll
    for (int j = 0; j < 4; ++j) {
      int i = base + j;
      int dv = 0;
      if (i < n) {
        dv = 1;
        #pragma unroll
        for (int k = 0; k < NPRIV; ++k) dv += degi8[(size_t)k * n + i];
      }
      d[j] = dv;
      t += dv;
    }
    __shared__ int sc[256];
    sc[tid] = t;
    __syncthreads();
    for (int off = 1; off < 256; off <<= 1) {
      int v = 0;
      if (tid >= off) v = sc[tid - off];
      __syncthreads();
      if (tid >= off) sc[tid] += v;
      __syncthreads();
    }
    int run = bsum[bb] + sc[tid] - t;
    #pragma unroll
    for (int j = 0; j < 4; ++j) {
      int i = base + j;
      if (i < n) {
        rowptr[i] = run;
        csrsrc[run] = i;       // self-loop occupies slot 0 of each row
        cursor[i] = run + 1;   // edges fill after it
        dinv[i] = rsqrtf((float)d[j]);
        run += d[j];
        if (i == n - 1) rowptr[n] = run;
      }
    }
  }
}

__global__ void k_scatter(const int* __restrict__ esrc, const int* __restrict__ edst, int E,
                          int* __restrict__ cursor, int* __restrict__ csrsrc) {
  int i = blockIdx.x * blockDim.x + threadIdx.x;
  if (i < E) {
    int d = edst[i];
    int p = atomicAdd(&cursor[d], 1);
    csrsrc[p] = esrc[i];
  }
}

// merge the two col-block logit partials: als = P0 + P1
__global__ void k_merge(const float* __restrict__ als2, const float* __restrict__ ald2,
                        float* __restrict__ als, float* __restrict__ ald, int n) {
  int i = blockIdx.x * blockDim.x + threadIdx.x;
  if (i < n) {
    als[i] = als2[i] + als2[n + i];
    ald[i] = ald2[i] + ald2[n + i];
  }
}

// ---------------- bf16 MFMA GEMM, 128x128 tile; optional row scale; optional fused attention logits ----------------
// If aS: this col-block's logit partial -> plain store als2[blockIdx.x*n + row] (no atomics)
__global__ __launch_bounds__(256) void k_mfma_gemm128(const u16* __restrict__ A, const u16* __restrict__ Bt,
                                                      u16* __restrict__ C, int M, int N, int K,
                                                      const float* __restrict__ rowScale,
                                                      const float* __restrict__ aS, const float* __restrict__ aD,
                                                      float* __restrict__ als2, float* __restrict__ ald2) {
  __shared__ u16 As[128 * 40];  // [128][32+8] pad -> 2-way (free) LDS banking
  __shared__ u16 Bs[128 * 40];
  int tid = threadIdx.x;
  int wave = tid >> 6, lane = tid & 63, quad = lane >> 4, l16 = lane & 15;
  int rowBase = blockIdx.y * 128, colBase = blockIdx.x * 128;
  f32x4 acc[2][8] = {};
  for (int k0 = 0; k0 < K; k0 += 32) {
    #pragma unroll
    for (int i = 0; i < 2; ++i) {
      int ch = tid + i * 256;
      int r = ch >> 2, cc = (ch & 3) * 8;
      int gr = min(rowBase + r, M - 1);  // clamp: junk rows never stored
      *(uint4*)&As[r * 40 + cc] = *(const uint4*)(A + (size_t)gr * K + k0 + cc);
      *(uint4*)&Bs[r * 40 + cc] = *(const uint4*)(Bt + (size_t)(colBase + r) * K + k0 + cc);
    }
    __syncthreads();
    short8 af0 = *(const short8*)&As[(wave * 32 + l16) * 40 + quad * 8];
    short8 af1 = *(const short8*)&As[(wave * 32 + 16 + l16) * 40 + quad * 8];
    #pragma unroll
    for (int j = 0; j < 8; ++j) {
      short8 bf = *(const short8*)&Bs[(j * 16 + l16) * 40 + quad * 8];
      acc[0][j] = __builtin_amdgcn_mfma_f32_16x16x32_bf16(af0, bf, acc[0][j], 0, 0, 0);
      acc[1][j] = __builtin_amdgcn_mfma_f32_16x16x32_bf16(af1, bf, acc[1][j], 0, 0, 0);
    }
    __syncthreads();
  }
  // C/D layout: col=lane&15, row=quad*4+reg
  #pragma unroll
  for (int i = 0; i < 2; ++i) {
    #pragma unroll
    for (int r = 0; r < 4; ++r) {
      int gr = rowBase + wave * 32 + i * 16 + quad * 4 + r;
      if (gr >= M) continue;
      float sc = rowScale ? rowScale[gr] : 1.0f;
      #pragma unroll
      for (int j = 0; j < 8; ++j) {
        int gc = colBase + j * 16 + l16;
        C[(size_t)gr * N + gc] = f2bf(acc[i][j][r] * sc);
      }
      if (aS) {  // this col-block's partial attention logits (plain store, no contention)
        float t1 = 0.f, t2 = 0.f;
        #pragma unroll
        for (int j = 0; j < 8; ++j) {
          int gc = colBase + j * 16 + l16;
          float v = acc[i][j][r];
          t1 = fmaf(v, aS[gc], t1);
          t2 = fmaf(v, aD[gc], t2);
        }
        #pragma unroll
        for (int off = 1; off < 16; off <<= 1) {
          t1 += __shfl_xor(t1, off);
          t2 += __shfl_xor(t2, off);
        }
        if (l16 == 0) {
          als2[(size_t)blockIdx.x * M + gr] = t1;
          ald2[(size_t)blockIdx.x * M + gr] = t2;
        }
      }
    }
  }
}

// ---------------- bf16 MFMA GEMM, 128x64 tile (generic N, used for final W2) ----------------
__global__ __launch_bounds__(256) void k_mfma_gemm(const u16* __restrict__ A, const u16* __restrict__ Bt,
                                                   u16* __restrict__ C, int M, int N, int K,
                                                   const float* __restrict__ rowScale) {
  __shared__ u16 As[128 * 40];
  __shared__ u16 Bs[64 * 40];
  int tid = threadIdx.x;
  int wave = tid >> 6, lane = tid & 63, quad = lane >> 4, l16 = lane & 15;
  int rowBase = blockIdx.y * 128, colBase = blockIdx.x * 64;
  f32x4 acc[2][4] = {};
  for (int k0 = 0; k0 < K; k0 += 32) {
    #pragma unroll
    for (int i = 0; i < 2; ++i) {
      int ch = tid + i * 256;
      int r = ch >> 2, cc = (ch & 3) * 8;
      int gr = rowBase + r;
      uint4 v = make_uint4(0, 0, 0, 0);
      if (gr < M) v = *(const uint4*)(A + (size_t)gr * K + k0 + cc);
      *(uint4*)&As[r * 40 + cc] = v;
    }
    {
      int r = tid >> 2, cc = (tid & 3) * 8;
      int gn = colBase + r;
      uint4 v = make_uint4(0, 0, 0, 0);
      if (gn < N) v = *(const uint4*)(Bt + (size_t)gn * K + k0 + cc);
      *(uint4*)&Bs[r * 40 + cc] = v;
    }
    __syncthreads();
    short8 af[2];
    af[0] = *(const short8*)&As[(wave * 32 + l16) * 40 + quad * 8];
    af[1] = *(const short8*)&As[(wave * 32 + 16 + l16) * 40 + quad * 8];
    short8 bf[4];
    #pragma unroll
    for (int j = 0; j < 4; ++j) bf[j] = *(const short8*)&Bs[(j * 16 + l16) * 40 + quad * 8];
    #pragma unroll
    for (int i = 0; i < 2; ++i)
      #pragma unroll
      for (int j = 0; j < 4; ++j)
        acc[i][j] = __builtin_amdgcn_mfma_f32_16x16x32_bf16(af[i], bf[j], acc[i][j], 0, 0, 0);
    __syncthreads();
  }
  #pragma unroll
  for (int i = 0; i < 2; ++i) {
    #pragma unroll
    for (int r = 0; r < 4; ++r) {
      int gr = rowBase + wave * 32 + i * 16 + quad * 4 + r;
      if (gr >= M) continue;
      float sc = rowScale ? rowScale[gr] : 1.0f;
      #pragma unroll
      for (int j = 0; j < 4; ++j) {
        int gc = colBase + j * 16 + l16;
        if (gc < N) C[(size_t)gr * N + gc] = f2bf(acc[i][j][r] * sc);
      }
    }
  }
}

// ---------------- GCN aggregate (rows pre-scaled by dinv[s]): out[d]=relu(dinv[d]*sum + b) ----------------
__global__ __launch_bounds__(256) void k_gcn_agg(const u16* __restrict__ hs, const int* __restrict__ rowptr,
                                                 const int* __restrict__ csrsrc, const float* __restrict__ dinv,
                                                 const float* __restrict__ bias, u16* __restrict__ out, int n) {
  int wave = (blockIdx.x * blockDim.x + threadIdx.x) >> 6;
  int lane = threadIdx.x & 63;
  int sub = lane >> 5, l = lane & 31;
  int w = wave * 2 + sub;
  if (w >= n) return;
  int p0 = rowptr[w], p1 = rowptr[w + 1];
  float a[8] = {};
  int p = p0;
  for (; p + 4 <= p1; p += 4) {
    int s0 = csrsrc[p], s1 = csrsrc[p + 1], s2 = csrsrc[p + 2], s3 = csrsrc[p + 3];
    uint4 v0 = *(const uint4*)(hs + (size_t)s0 * DD + l * 8);
    uint4 v1 = *(const uint4*)(hs + (size_t)s1 * DD + l * 8);
    uint4 v2 = *(const uint4*)(hs + (size_t)s2 * DD + l * 8);
    uint4 v3 = *(const uint4*)(hs + (size_t)s3 * DD + l * 8);
    acc8(a, v0); acc8(a, v1); acc8(a, v2); acc8(a, v3);
  }
  for (; p < p1; ++p) {
    int s = csrsrc[p];
    uint4 v = *(const uint4*)(hs + (size_t)s * DD + l * 8);
    acc8(a, v);
  }
  float dd = dinv[w];
  float4 b0 = ((const float4*)bias)[l * 2];
  float4 b1 = ((const float4*)bias)[l * 2 + 1];
  float r0 = fmaxf(dd * a[0] + b0.x, 0.f), r1 = fmaxf(dd * a[1] + b0.y, 0.f);
  float r2 = fmaxf(dd * a[2] + b0.z, 0.f), r3 = fmaxf(dd * a[3] + b0.w, 0.f);
  float r4 = fmaxf(dd * a[4] + b1.x, 0.f), r5 = fmaxf(dd * a[5] + b1.y, 0.f);
  float r6 = fmaxf(dd * a[6] + b1.z, 0.f), r7 = fmaxf(dd * a[7] + b1.w, 0.f);
  uint4 o;
  o.x = (uint)f2bf(r0) | ((uint)f2bf(r1) << 16);
  o.y = (uint)f2bf(r2) | ((uint)f2bf(r3) << 16);
  o.z = (uint)f2bf(r4) | ((uint)f2bf(r5) << 16);
  o.w = (uint)f2bf(r6) | ((uint)f2bf(r7) << 16);
  *(uint4*)(out + (size_t)w * DD + l * 8) = o;
}

// ---------------- GAT aggregate: online segment softmax + weighted sum + bias + relu ----------------
__global__ __launch_bounds__(256) void k_gat_agg(const u16* __restrict__ h, const int* __restrict__ rowptr,
                                                 const int* __restrict__ csrsrc, const float* __restrict__ als,
                                                 const float* __restrict__ ald, const float* __restrict__ bias,
                                                 u16* __restrict__ out, int n) {
  int wave = (blockIdx.x * blockDim.x + threadIdx.x) >> 6;
  int lane = threadIdx.x & 63;
  int sub = lane >> 5, l = lane & 31;
  int w = wave * 2 + sub;
  if (w >= n) return;
  float ad = ald[w];
  int p0 = rowptr[w], p1 = rowptr[w + 1];
  // pass 1: online softmax stats, lanes stride edges within half-wave
  float m = -1e30f, z = 0.f;
  for (int p = p0 + l; p < p1; p += 32) {
    float e = als[csrsrc[p]] + ad;
    e = (e > 0.f) ? e : NSLOPE * e;
    if (e > m) { z = z * __expf(m - e) + 1.f; m = e; }
    else z += __expf(e - m);
  }
  #pragma unroll
  for (int off = 16; off >= 1; off >>= 1) {
    float m2 = __shfl_xor(m, off), z2 = __shfl_xor(z, off);
    float M = fmaxf(m, m2);
    z = z * __expf(m - M) + z2 * __expf(m2 - M);
    m = M;
  }
  float invz = 1.0f / z;
  // pass 2: weighted feature accumulation, lane owns 8 features, unroll x4
  float a[8] = {};
  int p = p0;
  for (; p + 4 <= p1; p += 4) {
    int s0 = csrsrc[p], s1 = csrsrc[p + 1], s2 = csrsrc[p + 2], s3 = csrsrc[p + 3];
    float e0 = als[s0] + ad; e0 = (e0 > 0.f) ? e0 : NSLOPE * e0;
    float e1 = als[s1] + ad; e1 = (e1 > 0.f) ? e1 : NSLOPE * e1;
    float e2 = als[s2] + ad; e2 = (e2 > 0.f) ? e2 : NSLOPE * e2;
    float e3 = als[s3] + ad; e3 = (e3 > 0.f) ? e3 : NSLOPE * e3;
    uint4 v0 = *(const uint4*)(h + (size_t)s0 * DD + l * 8);
    uint4 v1 = *(const uint4*)(h + (size_t)s1 * DD + l * 8);
    uint4 v2 = *(const uint4*)(h + (size_t)s2 * DD + l * 8);
    uint4 v3 = *(const uint4*)(h + (size_t)s3 * DD + l * 8);
    wacc8(a, v0, __expf(e0 - m) * invz);
    wacc8(a, v1, __expf(e1 - m) * invz);
    wacc8(a, v2, __expf(e2 - m) * invz);
    wacc8(a, v3, __expf(e3 - m) * invz);
  }
  for (; p < p1; ++p) {
    int s = csrsrc[p];
    float e = als[s] + ad; e = (e > 0.f) ? e : NSLOPE * e;
    uint4 v = *(const uint4*)(h + (size_t)s * DD + l * 8);
    wacc8(a, v, __expf(e - m) * invz);
  }
  float4 b0 = ((const float4*)bias)[l * 2];
  float4 b1 = ((const float4*)bias)[l * 2 + 1];
  float r0 = fmaxf(a[0] + b0.x, 0.f), r1 = fmaxf(a[1] + b0.y, 0.f);
  float r2 = fmaxf(a[2] + b0.z, 0.f), r3 = fmaxf(a[3] + b0.w, 0.f);
  float r4 = fmaxf(a[4] + b1.x, 0.f), r5 = fmaxf(a[5] + b1.y, 0.f);
  float r6 = fmaxf(a[6] + b1.z, 0.f), r7 = fmaxf(a[7] + b1.w, 0.f);
  uint4 o;
  o.x = (uint)f2bf(r0) | ((uint)f2bf(r1) << 16);
  o.y = (uint)f2bf(r2) | ((uint)f2bf(r3) << 16);
  o.z = (uint)f2bf(r4) | ((uint)f2bf(r5) << 16);
  o.w = (uint)f2bf(r6) | ((uint)f2bf(r7) << 16);
  *(uint4*)(out + (size_t)w * DD + l * 8) = o;
}

// ---------------- final GCN (H->40, rows pre-scaled by dinv) + log_softmax, fp32 out ----------------
__global__ __launch_bounds__(256) void k_gcn2_lsm(const u16* __restrict__ hs, const int* __restrict__ rowptr,
                                                  const int* __restrict__ csrsrc, const float* __restrict__ dinv,
                                                  const float* __restrict__ bias, float* __restrict__ out, int n) {
  int w = (blockIdx.x * blockDim.x + threadIdx.x) >> 6;
  int lane = threadIdx.x & 63;
  if (w >= n) return;
  int p0 = rowptr[w], p1 = rowptr[w + 1];
  float acc = 0.f;
  int p = p0;
  for (; p + 4 <= p1; p += 4) {
    int s0 = csrsrc[p], s1 = csrsrc[p + 1], s2 = csrsrc[p + 2], s3 = csrsrc[p + 3];
    if (lane < LL) {
      float v0 = bf2f(hs[(size_t)s0 * LL + lane]);
      float v1 = bf2f(hs[(size_t)s1 * LL + lane]);
      float v2 = bf2f(hs[(size_t)s2 * LL + lane]);
      float v3 = bf2f(hs[(size_t)s3 * LL + lane]);
      acc += v0 + v1 + v2 + v3;
    }
  }
  for (; p < p1; ++p) {
    int s = csrsrc[p];
    if (lane < LL) acc += bf2f(hs[(size_t)s * LL + lane]);
  }
  float dd = dinv[w];
  float v = (lane < LL) ? dd * acc + bias[lane] : -INFINITY;
  float m = v;
  #pragma unroll
  for (int off = 1; off < 64; off <<= 1) m = fmaxf(m, __shfl_xor(m, off));
  float ex = (lane < LL) ? __expf(v - m) : 0.f;
  float z = ex;
  #pragma unroll
  for (int off = 1; off < 64; off <<= 1) z += __shfl_xor(z, off);
  if (lane < LL) out[(size_t)w * LL + lane] = v - m - logf(z);
}

// ---------------- launch ----------------
extern "C" void kernel_launch(void* const* d_in, const int* in_sizes, int n_in,
                              void* d_out, int out_size, void* d_ws, size_t ws_size,
                              hipStream_t stream) {
  const float* x   = (const float*)d_in[0];
  const int*   ei  = (const int*)d_in[1];
  const float* W1  = (const float*)d_in[2];
  const float* b1  = (const float*)d_in[3];
  const float* Wg  = (const float*)d_in[4];
  const float* a_s = (const float*)d_in[5];
  const float* a_d = (const float*)d_in[6];
  const float* bg  = (const float*)d_in[7];
  const float* W2  = (const float*)d_in[8];
  const float* b2  = (const float*)d_in[9];
  float* out = (float*)d_out;

  const int n = in_sizes[0] / DD;
  const int E = in_sizes[1] / 2;
  const int M = E + n;
  const int* esrc = ei;
  const int* edst = ei + E;

  char* wp = (char*)d_ws;
  auto carve = [&](size_t bytes) -> char* {
    char* p = wp;
    wp += (bytes + 255) & ~(size_t)255;
    return p;
  };
  const int rowsPerBlk = 32;
  int nbC = (n + rowsPerBlk - 1) / rowsPerBlk;   // colstats blocks
  int nbE = (E + 255) / 256;                     // count_deg blocks
  int nb  = (n + SCHUNK - 1) / SCHUNK;           // scan chunks
  int total4 = n * (DD / 4);
  int nbS = (total4 + 255) / 256;                // standardize blocks

  u16*   buf0   = (u16*)carve((size_t)n * DD * 2);
  u16*   buf1   = (u16*)carve((size_t)n * DD * 2);
  u16*   h40    = (u16*)carve((size_t)n * LL * 2);
  u16*   W1t    = (u16*)carve((size_t)DD * DD * 2);
  u16*   Wgt    = (u16*)carve((size_t)DD * DD * 2);
  u16*   W2t    = (u16*)carve((size_t)LL * DD * 2);
  int*   csrsrc = (int*)carve((size_t)M * 4);
  int*   rowptr = (int*)carve((size_t)(n + 1) * 4);
  int*   cursor = (int*)carve((size_t)n * 4);
  int*   degi8  = (int*)carve((size_t)NPRIV * n * 4);
  int*   bsum   = (int*)carve(64 * 4);
  float* dinv   = (float*)carve((size_t)n * 4);
  float* als2   = (float*)carve((size_t)2 * n * 4);   // per-colblock logit partials
  float* ald2   = (float*)carve((size_t)2 * n * 4);
  float* alsA   = (float*)carve((size_t)n * 4);       // merged logits
  float* aldA   = (float*)carve((size_t)n * 4);
  float* partS  = (float*)carve((size_t)nbC * DD * 4);
  float* partQ  = (float*)carve((size_t)nbC * DD * 4);
  float* csum   = (float*)carve(DD * 4);
  float* csq    = (float*)carve(DD * 4);
  float* mean   = (float*)carve(DD * 4);
  float* rstd   = (float*)carve(DD * 4);

  hipMemsetAsync(degi8, 0, (size_t)NPRIV * n * 4, stream);
  hipMemsetAsync(csum, 0, DD * 4, stream);
  hipMemsetAsync(csq, 0, DD * 4, stream);

  // fused preprocessing (atomic-light)
  k_pre1<<<nbC + nbE + 3 * DD, 256, 0, stream>>>(x, partS, partQ, n, rowsPerBlk, nbC,
                                                 edst, E, degi8, nbE, W1, W1t, Wg, Wgt, W2, W2t);
  k_pre2<<<nb + 16, 256, 0, stream>>>(degi8, bsum, nb, n, partS, partQ, csum, csq, nbC);
  k_pre3<<<2, 256, 0, stream>>>(bsum, nb, csum, csq, mean, rstd, n);
  k_pre4<<<nbS + nb, 256, 0, stream>>>(x, mean, rstd, buf0, total4, nbS,
                                       degi8, bsum, rowptr, cursor, csrsrc, dinv, n);
  k_scatter<<<(E + 255) / 256, 256, 0, stream>>>(esrc, edst, E, cursor, csrsrc);

  dim3 blk(256);
  dim3 gemmGrid(DD / 128, (n + 127) / 128);   // 128x128 tiles for square GEMMs
  int aggGrid1 = (n + 3) / 4;   // 1 wave per node (k_gcn2_lsm)
  int aggGrid2 = (n + 7) / 8;   // 2 nodes per wave
  int mergeGrid = (n + 255) / 256;

  // layer 1: GCN(256->256) + relu  (GEMM epilogue pre-scales rows by dinv)
  k_mfma_gemm128<<<gemmGrid, blk, 0, stream>>>(buf0, W1t, buf1, n, DD, DD, dinv,
                                               nullptr, nullptr, nullptr, nullptr);
  k_gcn_agg<<<aggGrid2, blk, 0, stream>>>(buf1, rowptr, csrsrc, dinv, b1, buf0, n);

  // layer 2: GAT — GEMM emits h2 and per-colblock logit partials; merge; aggregate
  k_mfma_gemm128<<<gemmGrid, blk, 0, stream>>>(buf0, Wgt, buf1, n, DD, DD, nullptr,
                                               a_s, a_d, als2, ald2);
  k_merge<<<mergeGrid, blk, 0, stream>>>(als2, ald2, alsA, aldA, n);
  k_gat_agg<<<aggGrid2, blk, 0, stream>>>(buf1, rowptr, csrsrc, alsA, aldA, bg, buf0, n);

  // layer 3: GAT — same pattern (als2/ald2 safely reused; in-stream ordering)
  k_mfma_gemm128<<<gemmGrid, blk, 0, stream>>>(buf0, Wgt, buf1, n, DD, DD, nullptr,
                                               a_s, a_d, als2, ald2);
  k_merge<<<mergeGrid, blk, 0, stream>>>(als2, ald2, alsA, aldA, n);
  k_gat_agg<<<aggGrid2, blk, 0, stream>>>(buf1, rowptr, csrsrc, alsA, aldA, bg, buf0, n);

  // final: GCN(256->40) + log_softmax (rows pre-scaled by dinv)
  dim3 gemmGrid2(1, (n + 127) / 128);
  k_mfma_gemm<<<gemmGrid2, blk, 0, stream>>>(buf0, W2t, h40, n, LL, DD, dinv);
  k_gcn2_lsm<<<aggGrid1, blk, 0, stream>>>(h40, rowptr, csrsrc, dinv, b2, out, n);
}